// Round 1
// 392.894 us; speedup vs baseline: 1.0741x; 1.0741x over previous
//
#include <hip/hip_runtime.h>

#define N_NODES 50000
#define N_EDGES 800000
#define C_IN    128
#define C_HID   256
#define C_OUT   128
#define YSTRIDE 512       // bf16: [y_src 0..255 | y_dst 256..511]; after fused kernel,
                          // ch 256..415 of each row are overwritten with segb
                          // [z-mean 0..127 | attr 128 | zeros 129..159]

typedef __bf16 bf16x8 __attribute__((ext_vector_type(8)));
typedef float  f32x4  __attribute__((ext_vector_type(4)));

__device__ __forceinline__ unsigned short f2bf(float x) {
    unsigned u = __float_as_uint(x);
    u = (u + 0x7FFF + ((u >> 16) & 1)) >> 16;   // RNE
    return (unsigned short)u;
}

// ---------- fused prep: cast_z | hist | bpack | wa1b | wa2b ----------
__global__ __launch_bounds__(256) void prep_kernel(
    const float* __restrict__ z, const int* __restrict__ ei,
    const float* __restrict__ We1, const float* __restrict__ Wa1,
    const float* __restrict__ Wa2,
    unsigned short* __restrict__ zb, int* __restrict__ cnt,
    unsigned short* __restrict__ Bpack, unsigned short* __restrict__ Wa1b,
    unsigned short* __restrict__ Wa2b)
{
    const int b = blockIdx.x;
    const int tid = threadIdx.x;
    if (b < 6250) {                                   // cast_z: 6250*256 = 1.6M float4
        int t = b * 256 + tid;
        float4 v = ((const float4*)z)[t];
        ushort4 o;
        o.x = f2bf(v.x); o.y = f2bf(v.y); o.z = f2bf(v.z); o.w = f2bf(v.w);
        ((ushort4*)zb)[t] = o;
    } else if (b < 6250 + 3125) {                     // hist: 3125*256 = 800000
        int e = (b - 6250) * 256 + tid;
        atomicAdd(&cnt[ei[N_EDGES + e]], 1);
    } else if (b < 6250 + 3125 + 32) {                // Bpack (We1 B-frags, 8ks x 16nt)
        int t = (b - 6250 - 3125) * 256 + tid;        // 8192 lane-slots
        int lane = t & 63, nt = (t >> 6) & 15, ks = t >> 10;
        int n  = nt * 16 + (lane & 15);
        int kb = ks * 32 + (lane >> 4) * 8;
        #pragma unroll
        for (int j = 0; j < 8; ++j)
            Bpack[t * 8 + j] = f2bf(We1[(kb + j) * C_HID + n]);
    } else if (b < 6250 + 3125 + 32 + 20) {           // Wa1b (node layer1)
        int t = (b - 6250 - 3125 - 32) * 256 + tid;
        if (t >= 5 * 16 * 64) return;
        int lane = t & 63, nt = (t >> 6) & 15, ks = t >> 10;
        int n = nt * 16 + (lane & 15);
        #pragma unroll
        for (int j = 0; j < 8; ++j) {
            int k = ks * 32 + (lane >> 4) * 8 + j;
            float v = 0.f;
            if (k < 128)       v = Wa1[(k + 1) * C_HID + n];
            else if (k == 128) v = Wa1[0 * C_HID + n];
            Wa1b[t * 8 + j] = f2bf(v);
        }
    } else {                                          // Wa2b (node layer2)
        int t = (b - 6250 - 3125 - 32 - 20) * 256 + tid;
        if (t >= 8 * 8 * 64) return;
        int lane = t & 63, nt = (t >> 6) & 7, ks = t >> 9;
        int n  = nt * 16 + (lane & 15);
        int kb = ks * 32 + (lane >> 4) * 8;
        #pragma unroll
        for (int j = 0; j < 8; ++j)
            Wa2b[t * 8 + j] = f2bf(Wa2[(kb + j) * C_OUT + n]);
    }
}

// ---------- CSR build ----------

// cnt zero-padded to 50176 ints so int4 reads need no bounds checks.
__global__ __launch_bounds__(256) void scan_kernel(const int* __restrict__ cnt,
                                                   int* __restrict__ offsets) {
    const int tid = threadIdx.x;
    const int per = 196;                        // 49 int4
    const int base = tid * per;
    const int4* c4 = (const int4*)(cnt + base);
    int sum = 0;
    #pragma unroll 7
    for (int i = 0; i < 49; ++i) {
        int4 v = c4[i];
        sum += v.x + v.y + v.z + v.w;
    }
    const int lane = tid & 63, w = tid >> 6;
    int v = sum;
    #pragma unroll
    for (int off = 1; off < 64; off <<= 1) {
        int t = __shfl_up(v, off, 64);
        if (lane >= off) v += t;
    }
    __shared__ int s_w[4];
    if (lane == 63) s_w[w] = v;
    __syncthreads();
    int wbase = 0;
    for (int i = 0; i < w; ++i) wbase += s_w[i];
    int run = wbase + v - sum;
    for (int i = 0; i < per; ++i) {
        int b = base + i;
        if (b < N_NODES) { offsets[b] = run; run += cnt[b]; }
    }
    if (tid == 255) offsets[N_NODES] = run;
}

__global__ void fill_kernel(const int* __restrict__ ei, const float* __restrict__ eattr,
                            const int* __restrict__ offsets, int* __restrict__ cursor,
                            int* __restrict__ esrc, int* __restrict__ perm,
                            float* __restrict__ eatt) {
    int e = blockIdx.x * 256 + threadIdx.x;
    if (e >= N_EDGES) return;
    int d = ei[N_EDGES + e];
    int pos = atomicAdd(&cursor[d], 1);
    int slot = offsets[d] + pos;
    esrc[slot] = ei[e];
    perm[slot] = e;
    eatt[slot] = eattr[e];
}

// ---------- Y GEMM: Y[:,0:256] = zb@We1_top ; Y[:,256:512] = zb@We1_bot + be1 ----------
// M=50048 x K=128 x N=256 per half; grid (782, 2), 256 thr / 4 waves,
// wave owns 64 cols of this half. Reuses Bpack: ks 0..3 = W_top, 4..7 = W_bot.
__global__ __launch_bounds__(256, 2) void ygemm_kernel(
    const unsigned short* __restrict__ zb, const unsigned short* __restrict__ Bpack,
    const float* __restrict__ be1, unsigned short* __restrict__ Y)
{
    __shared__ __align__(16) unsigned short s_a[64][136];
    const int tid = threadIdx.x;
    const int lane = tid & 63, w = tid >> 6;
    const int m16 = lane & 15, quad = lane >> 4;
    const int n0 = blockIdx.x * 64;
    const int half = blockIdx.y;

    // stage A: 64 rows x 256B = 1024 16B-chunks, 4/thread
    #pragma unroll
    for (int i = 0; i < 4; ++i) {
        int c = tid + i * 256;
        int row = c >> 4, col = (c & 15) * 8;
        *(uint4*)&s_a[row][col] = *(const uint4*)(zb + (size_t)(n0 + row) * C_IN + col);
    }

    bf16x8 bfr[4][4];
    {
        const bf16x8* bp = (const bf16x8*)Bpack;
        #pragma unroll
        for (int ks = 0; ks < 4; ++ks)
            #pragma unroll
            for (int nt = 0; nt < 4; ++nt)
                bfr[ks][nt] = bp[((half * 4 + ks) * 16 + (w * 4 + nt)) * 64 + lane];
    }
    __syncthreads();

    f32x4 acc[4][4];
    #pragma unroll
    for (int mt = 0; mt < 4; ++mt)
        #pragma unroll
        for (int nt = 0; nt < 4; ++nt)
            acc[mt][nt] = (f32x4){0.f, 0.f, 0.f, 0.f};

    #pragma unroll
    for (int ks = 0; ks < 4; ++ks) {
        #pragma unroll
        for (int mt = 0; mt < 4; ++mt) {
            bf16x8 a = *(const bf16x8*)&s_a[mt * 16 + m16][ks * 32 + quad * 8];
            #pragma unroll
            for (int nt = 0; nt < 4; ++nt)
                acc[mt][nt] = __builtin_amdgcn_mfma_f32_16x16x32_bf16(
                    a, bfr[ks][nt], acc[mt][nt], 0, 0, 0);
        }
    }

    #pragma unroll
    for (int nt = 0; nt < 4; ++nt) {
        const int c = w * 64 + nt * 16 + m16;           // col within half
        const float b = half ? be1[c] : 0.f;
        #pragma unroll
        for (int mt = 0; mt < 4; ++mt)
            #pragma unroll
            for (int r = 0; r < 4; ++r) {
                const int node = n0 + mt * 16 + quad * 4 + r;
                Y[(size_t)node * YSTRIDE + half * 256 + c] = f2bf(acc[mt][nt][r] + b);
            }
    }
}

// ---------- fused edge elementwise + gather-mean (per-dst-node wave) ----------
// One wave per dst node. Y_hi[dst] + We2 hoisted to registers once per node
// (CSR re-read of the dst row per edge eliminated). Edge dot: 16 lanes per
// edge x 16 channels per lane -> reduce is 4 xor stages on ONE register per
// 4 edges (vs 6 stages x 4 regs in the old 64-lane butterfly). The z-mean
// accumulation (all 64 lanes, 2 ch each) shares the same esrc loads and loop.
// After the edge loop, segb is written into the node's own Y_hi bytes
// (ch 256..415): this wave already consumed Y_hi[n], and src gathers only
// touch Y_lo, so the in-place overwrite is race-free.
__device__ __forceinline__ float dot8(uint4 q, const float* __restrict__ d,
                                      const float* __restrict__ wv, float p) {
    const unsigned u[4] = {q.x, q.y, q.z, q.w};
    #pragma unroll
    for (int j = 0; j < 4; ++j) {
        const float lo = __uint_as_float(u[j] << 16)         + d[2 * j];
        const float hi = __uint_as_float(u[j] & 0xffff0000u) + d[2 * j + 1];
        p = fmaf(fmaxf(lo, 0.f), wv[2 * j],     p);
        p = fmaf(fmaxf(hi, 0.f), wv[2 * j + 1], p);
    }
    return p;
}

__global__ __launch_bounds__(256) void fused_eg_kernel(
    unsigned short* __restrict__ Y, const unsigned short* __restrict__ zb,
    const int* __restrict__ offsets, const int* __restrict__ esrc,
    const int* __restrict__ perm, const float* __restrict__ eatt,
    const float* __restrict__ We2, const float* __restrict__ be2,
    float* __restrict__ edge_out)
{
    const int w = threadIdx.x >> 6, lane = threadIdx.x & 63;
    const int n = blockIdx.x * 4 + w;
    if (n >= N_NODES) return;
    const int c = lane & 15, g = lane >> 4;           // 16 lanes per edge-slot
    const int beg = offsets[n], end = offsets[n + 1], deg = end - beg;
    const float be2v = be2[0];

    // hoist dst half-row (ch c*8+0..7 and 128+c*8+0..7) + matching We2
    float d0[8], d1[8], w0[8], w1[8];
    {
        const unsigned short* yh = Y + (size_t)n * YSTRIDE + 256;
        uint4 q0 = *(const uint4*)(yh + c * 8);
        uint4 q1 = *(const uint4*)(yh + 128 + c * 8);
        const unsigned a0[4] = {q0.x, q0.y, q0.z, q0.w};
        const unsigned a1[4] = {q1.x, q1.y, q1.z, q1.w};
        #pragma unroll
        for (int j = 0; j < 4; ++j) {
            d0[2 * j]     = __uint_as_float(a0[j] << 16);
            d0[2 * j + 1] = __uint_as_float(a0[j] & 0xffff0000u);
            d1[2 * j]     = __uint_as_float(a1[j] << 16);
            d1[2 * j + 1] = __uint_as_float(a1[j] & 0xffff0000u);
        }
        #pragma unroll
        for (int j = 0; j < 8; ++j) {
            w0[j] = We2[c * 8 + j];
            w1[j] = We2[128 + c * 8 + j];
        }
    }

    float ax = 0.f, ay = 0.f;                  // lane owns z-channels lane*2, lane*2+1
    int i = beg;
    for (; i + 4 <= end; i += 4) {
        const int s0 = esrc[i], s1 = esrc[i + 1], s2 = esrc[i + 2], s3 = esrc[i + 3];
        // z-mean: all 64 lanes, all 4 edges
        const unsigned u0 = *(const unsigned*)(zb + (size_t)s0 * C_IN + lane * 2);
        const unsigned u1 = *(const unsigned*)(zb + (size_t)s1 * C_IN + lane * 2);
        const unsigned u2 = *(const unsigned*)(zb + (size_t)s2 * C_IN + lane * 2);
        const unsigned u3 = *(const unsigned*)(zb + (size_t)s3 * C_IN + lane * 2);
        ax += __uint_as_float(u0 << 16) + __uint_as_float(u1 << 16)
            + __uint_as_float(u2 << 16) + __uint_as_float(u3 << 16);
        ay += __uint_as_float(u0 & 0xffff0000u) + __uint_as_float(u1 & 0xffff0000u)
            + __uint_as_float(u2 & 0xffff0000u) + __uint_as_float(u3 & 0xffff0000u);
        // edge dot: group g owns edge i+g
        const int sg = (g == 0) ? s0 : (g == 1) ? s1 : (g == 2) ? s2 : s3;
        const unsigned short* yr = Y + (size_t)sg * YSTRIDE;
        const uint4 q0 = *(const uint4*)(yr + c * 8);
        const uint4 q1 = *(const uint4*)(yr + 128 + c * 8);
        float p = dot8(q0, d0, w0, 0.f);
        p = dot8(q1, d1, w1, p);
        p += __shfl_xor(p, 1, 64);
        p += __shfl_xor(p, 2, 64);
        p += __shfl_xor(p, 4, 64);
        p += __shfl_xor(p, 8, 64);
        if (c == 0) edge_out[perm[i + g]] = p + be2v;
    }
    for (; i < end; ++i) {                     // tail (<=3 edges)
        const int s = esrc[i];
        const unsigned u = *(const unsigned*)(zb + (size_t)s * C_IN + lane * 2);
        ax += __uint_as_float(u << 16);
        ay += __uint_as_float(u & 0xffff0000u);
        const unsigned short* yr = Y + (size_t)s * YSTRIDE;
        const uint4 q0 = *(const uint4*)(yr + c * 8);
        const uint4 q1 = *(const uint4*)(yr + 128 + c * 8);
        float p = dot8(q0, d0, w0, 0.f);
        p = dot8(q1, d1, w1, p);
        p += __shfl_xor(p, 1, 64);
        p += __shfl_xor(p, 2, 64);
        p += __shfl_xor(p, 4, 64);
        p += __shfl_xor(p, 8, 64);
        if (lane == 0) edge_out[perm[i]] = p + be2v;
    }

    float asum = 0.f;
    for (int j = beg + lane; j < end; j += 64) asum += eatt[j];
    #pragma unroll
    for (int off = 1; off < 64; off <<= 1) asum += __shfl_xor(asum, off, 64);

    const float inv = (deg > 0) ? 1.0f / (float)deg : 0.0f;
    unsigned short* segn = Y + (size_t)n * YSTRIDE + 256;   // in-place: Y_hi is dead now
    ushort2 o; o.x = f2bf(ax * inv); o.y = f2bf(ay * inv);
    *(ushort2*)(segn + lane * 2) = o;
    if (lane < 16) {
        ushort2 pz; pz.x = (lane == 0) ? f2bf(asum * inv) : (unsigned short)0; pz.y = 0;
        *(ushort2*)(segn + 128 + lane * 2) = pz;   // attr @128, zeros 129..159
    }
}

// ---------- node MLP: bf16 MFMA, both layers, h via LDS round-trip ----------
// segb lives in Y ch 256..415 of each row (stride YSTRIDE).
__global__ __launch_bounds__(256, 2) void node_mfma_kernel(
    const unsigned short* __restrict__ segb, const unsigned short* __restrict__ Wa1b,
    const float* __restrict__ ba1, const unsigned short* __restrict__ Wa2b,
    const float* __restrict__ ba2, float* __restrict__ x_out)
{
    __shared__ __align__(16) unsigned short s_a[64][168];
    __shared__ __align__(16) unsigned short s_h[64][264];
    const int tid  = threadIdx.x;
    const int lane = tid & 63, w = tid >> 6;
    const int m16 = lane & 15, quad = lane >> 4;
    const int n0 = blockIdx.x * 64;

    {
        const unsigned short* src = segb + (size_t)n0 * YSTRIDE + 256;
        #pragma unroll
        for (int i = 0; i < 5; ++i) {
            int c = tid + i * 256;
            int row = c / 20, col = c - row * 20;
            *(uint4*)&s_a[row][col * 8] =
                *(const uint4*)(src + (size_t)row * YSTRIDE + col * 8);
        }
    }

    bf16x8 bfr1[5][4];
    {
        const bf16x8* bp = (const bf16x8*)Wa1b;
        #pragma unroll
        for (int ks = 0; ks < 5; ++ks)
            #pragma unroll
            for (int nt = 0; nt < 4; ++nt)
                bfr1[ks][nt] = bp[(ks * 16 + (w * 4 + nt)) * 64 + lane];
    }
    __syncthreads();

    f32x4 acc1[4][4];
    #pragma unroll
    for (int mt = 0; mt < 4; ++mt)
        #pragma unroll
        for (int nt = 0; nt < 4; ++nt)
            acc1[mt][nt] = (f32x4){0.f, 0.f, 0.f, 0.f};

    #pragma unroll
    for (int ks = 0; ks < 5; ++ks) {
        #pragma unroll
        for (int mt = 0; mt < 4; ++mt) {
            bf16x8 a = *(const bf16x8*)&s_a[mt * 16 + m16][ks * 32 + quad * 8];
            #pragma unroll
            for (int nt = 0; nt < 4; ++nt)
                acc1[mt][nt] = __builtin_amdgcn_mfma_f32_16x16x32_bf16(
                    a, bfr1[ks][nt], acc1[mt][nt], 0, 0, 0);
        }
    }

    #pragma unroll
    for (int nt = 0; nt < 4; ++nt) {
        const int chan = w * 64 + nt * 16 + m16;
        const float b1 = ba1[chan];
        #pragma unroll
        for (int mt = 0; mt < 4; ++mt)
            #pragma unroll
            for (int r = 0; r < 4; ++r) {
                const int node = mt * 16 + quad * 4 + r;
                s_h[node][chan] = f2bf(fmaxf(acc1[mt][nt][r] + b1, 0.f));
            }
    }

    bf16x8 bfr2[8][2];
    {
        const bf16x8* bp = (const bf16x8*)Wa2b;
        #pragma unroll
        for (int ks = 0; ks < 8; ++ks)
            #pragma unroll
            for (int nt = 0; nt < 2; ++nt)
                bfr2[ks][nt] = bp[(ks * 8 + (w * 2 + nt)) * 64 + lane];
    }
    __syncthreads();

    f32x4 acc2[4][2];
    #pragma unroll
    for (int mt = 0; mt < 4; ++mt)
        #pragma unroll
        for (int nt = 0; nt < 2; ++nt)
            acc2[mt][nt] = (f32x4){0.f, 0.f, 0.f, 0.f};

    #pragma unroll
    for (int ks = 0; ks < 8; ++ks) {
        #pragma unroll
        for (int mt = 0; mt < 4; ++mt) {
            bf16x8 a = *(const bf16x8*)&s_h[mt * 16 + m16][ks * 32 + quad * 8];
            #pragma unroll
            for (int nt = 0; nt < 2; ++nt)
                acc2[mt][nt] = __builtin_amdgcn_mfma_f32_16x16x32_bf16(
                    a, bfr2[ks][nt], acc2[mt][nt], 0, 0, 0);
        }
    }

    #pragma unroll
    for (int nt = 0; nt < 2; ++nt) {
        const int j = w * 32 + nt * 16 + m16;
        const float b2 = ba2[j];
        #pragma unroll
        for (int mt = 0; mt < 4; ++mt)
            #pragma unroll
            for (int r = 0; r < 4; ++r) {
                const int node = n0 + mt * 16 + quad * 4 + r;
                if (node < N_NODES)
                    x_out[(size_t)node * C_OUT + j] = acc2[mt][nt][r] + b2;
            }
    }
}

// ---------- launch ----------
// ws layout (bytes), total ~74.5 MB:
//   Y       51,249,152   (50048 x 512 bf16; ch 256..415 become segb in-place)
//   zb      12,812,288   (50048 rows; 50000 valid, tail garbage never used)
//   Bpack      131,072
//   Wa1b        81,920
//   Wa2b        65,536
//   cnt        200,704   (50176 ints, zero-padded for int4 scan)
//   cursor     200,704
//   offsets    200,064
//   esrc     3,200,000
//   perm     3,200,000
//   eatt     3,200,000

extern "C" void kernel_launch(void* const* d_in, const int* in_sizes, int n_in,
                              void* d_out, int out_size, void* d_ws, size_t ws_size,
                              hipStream_t stream) {
    const float* z     = (const float*)d_in[0];
    const int*   ei    = (const int*)d_in[1];     // int32 per harness contract
    const float* eattr = (const float*)d_in[2];
    const float* Wa1   = (const float*)d_in[3];
    const float* ba1   = (const float*)d_in[4];
    const float* Wa2   = (const float*)d_in[5];
    const float* ba2   = (const float*)d_in[6];
    const float* We1   = (const float*)d_in[7];
    const float* be1   = (const float*)d_in[8];
    const float* We2   = (const float*)d_in[9];
    const float* be2   = (const float*)d_in[10];

    float* x_out    = (float*)d_out;
    float* edge_out = x_out + (size_t)N_NODES * C_OUT;

    char* wsb = (char*)d_ws;
    size_t off = 0;
    unsigned short* Y       = (unsigned short*)(wsb + off); off += 51249152;
    unsigned short* zb      = (unsigned short*)(wsb + off); off += 12812288;
    unsigned short* Bpack   = (unsigned short*)(wsb + off); off += 131072;
    unsigned short* Wa1b    = (unsigned short*)(wsb + off); off += 81920;
    unsigned short* Wa2b    = (unsigned short*)(wsb + off); off += 65536;
    int*            cnt     = (int*)(wsb + off);            off += 200704;
    int*            cursor  = (int*)(wsb + off);            off += 200704;
    int*            offsets = (int*)(wsb + off);            off += 200064;
    int*            esrc    = (int*)(wsb + off);            off += 3200000;
    int*            perm    = (int*)(wsb + off);            off += 3200000;
    float*          eatt    = (float*)(wsb + off);          off += 3200000;

    hipMemsetAsync(cnt, 0, 2 * 200704, stream);   // cnt + cursor (adjacent)

    prep_kernel<<<6250 + 3125 + 32 + 20 + 16, 256, 0, stream>>>(
        z, ei, We1, Wa1, Wa2, zb, cnt, Bpack, Wa1b, Wa2b);

    scan_kernel<<<1, 256, 0, stream>>>(cnt, offsets);
    fill_kernel<<<(N_EDGES + 255) / 256, 256, 0, stream>>>(ei, eattr, offsets, cursor,
                                                           esrc, perm, eatt);

    ygemm_kernel<<<dim3(782, 2), 256, 0, stream>>>(zb, Bpack, be1, Y);

    fused_eg_kernel<<<(N_NODES + 3) / 4, 256, 0, stream>>>(
        Y, zb, offsets, esrc, perm, eatt, We2, be2, edge_out);

    node_mfma_kernel<<<(N_NODES + 63) / 64, 256, 0, stream>>>(Y, Wa1b, ba1, Wa2b,
                                                              ba2, x_out);
}

// Round 2
// 390.623 us; speedup vs baseline: 1.0803x; 1.0058x over previous
//
#include <hip/hip_runtime.h>

#define N_NODES 50000
#define N_EDGES 800000
#define C_IN    128
#define C_HID   256
#define C_OUT   128
#define YSTRIDE 512       // bf16: [y_src 0..255 | y_dst 256..511]; after fused kernel,
                          // ch 256..415 of each row are overwritten with segb
                          // [z-mean 0..127 | attr 128 | zeros 129..159]

typedef __bf16 bf16x8 __attribute__((ext_vector_type(8)));
typedef float  f32x4  __attribute__((ext_vector_type(4)));

__device__ __forceinline__ unsigned short f2bf(float x) {
    unsigned u = __float_as_uint(x);
    u = (u + 0x7FFF + ((u >> 16) & 1)) >> 16;   // RNE
    return (unsigned short)u;
}

// ---------- fused prep: cast_z | hist | bpack | wa1b | wa2b ----------
__global__ __launch_bounds__(256) void prep_kernel(
    const float* __restrict__ z, const int* __restrict__ ei,
    const float* __restrict__ We1, const float* __restrict__ Wa1,
    const float* __restrict__ Wa2,
    unsigned short* __restrict__ zb, int* __restrict__ cnt,
    unsigned short* __restrict__ Bpack, unsigned short* __restrict__ Wa1b,
    unsigned short* __restrict__ Wa2b)
{
    const int b = blockIdx.x;
    const int tid = threadIdx.x;
    if (b < 6250) {                                   // cast_z: 6250*256 = 1.6M float4
        int t = b * 256 + tid;
        float4 v = ((const float4*)z)[t];
        ushort4 o;
        o.x = f2bf(v.x); o.y = f2bf(v.y); o.z = f2bf(v.z); o.w = f2bf(v.w);
        ((ushort4*)zb)[t] = o;
    } else if (b < 6250 + 3125) {                     // hist: 3125*256 = 800000
        int e = (b - 6250) * 256 + tid;
        atomicAdd(&cnt[ei[N_EDGES + e]], 1);
    } else if (b < 6250 + 3125 + 32) {                // Bpack (We1 B-frags, 8ks x 16nt)
        int t = (b - 6250 - 3125) * 256 + tid;        // 8192 lane-slots
        int lane = t & 63, nt = (t >> 6) & 15, ks = t >> 10;
        int n  = nt * 16 + (lane & 15);
        int kb = ks * 32 + (lane >> 4) * 8;
        #pragma unroll
        for (int j = 0; j < 8; ++j)
            Bpack[t * 8 + j] = f2bf(We1[(kb + j) * C_HID + n]);
    } else if (b < 6250 + 3125 + 32 + 20) {           // Wa1b (node layer1)
        int t = (b - 6250 - 3125 - 32) * 256 + tid;
        if (t >= 5 * 16 * 64) return;
        int lane = t & 63, nt = (t >> 6) & 15, ks = t >> 10;
        int n = nt * 16 + (lane & 15);
        #pragma unroll
        for (int j = 0; j < 8; ++j) {
            int k = ks * 32 + (lane >> 4) * 8 + j;
            float v = 0.f;
            if (k < 128)       v = Wa1[(k + 1) * C_HID + n];
            else if (k == 128) v = Wa1[0 * C_HID + n];
            Wa1b[t * 8 + j] = f2bf(v);
        }
    } else {                                          // Wa2b (node layer2)
        int t = (b - 6250 - 3125 - 32 - 20) * 256 + tid;
        if (t >= 8 * 8 * 64) return;
        int lane = t & 63, nt = (t >> 6) & 7, ks = t >> 9;
        int n  = nt * 16 + (lane & 15);
        int kb = ks * 32 + (lane >> 4) * 8;
        #pragma unroll
        for (int j = 0; j < 8; ++j)
            Wa2b[t * 8 + j] = f2bf(Wa2[(kb + j) * C_OUT + n]);
    }
}

// ---------- CSR build ----------

// cnt zero-padded to 50176 ints so int4 reads need no bounds checks.
__global__ __launch_bounds__(256) void scan_kernel(const int* __restrict__ cnt,
                                                   int* __restrict__ offsets) {
    const int tid = threadIdx.x;
    const int per = 196;                        // 49 int4
    const int base = tid * per;
    const int4* c4 = (const int4*)(cnt + base);
    int sum = 0;
    #pragma unroll 7
    for (int i = 0; i < 49; ++i) {
        int4 v = c4[i];
        sum += v.x + v.y + v.z + v.w;
    }
    const int lane = tid & 63, w = tid >> 6;
    int v = sum;
    #pragma unroll
    for (int off = 1; off < 64; off <<= 1) {
        int t = __shfl_up(v, off, 64);
        if (lane >= off) v += t;
    }
    __shared__ int s_w[4];
    if (lane == 63) s_w[w] = v;
    __syncthreads();
    int wbase = 0;
    for (int i = 0; i < w; ++i) wbase += s_w[i];
    int run = wbase + v - sum;
    for (int i = 0; i < per; ++i) {
        int b = base + i;
        if (b < N_NODES) { offsets[b] = run; run += cnt[b]; }
    }
    if (tid == 255) offsets[N_NODES] = run;
}

// One scattered 16-B store per edge (was 3 scattered 4-B stores to 3 arrays).
// Slot position via atomicSub on cnt (cnt is dead after scan; saves cursor array).
__global__ void fill_kernel(const int* __restrict__ ei, const float* __restrict__ eattr,
                            const int* __restrict__ offsets, int* __restrict__ cnt,
                            int4* __restrict__ erec) {
    int e = blockIdx.x * 256 + threadIdx.x;
    if (e >= N_EDGES) return;
    int d = ei[N_EDGES + e];
    int pos = atomicSub(&cnt[d], 1) - 1;
    int slot = offsets[d] + pos;
    erec[slot] = make_int4(ei[e], e, __float_as_int(eattr[e]), 0);
}

// ---------- Y GEMM: Y[:,0:256] = zb@We1_top ; Y[:,256:512] = zb@We1_bot + be1 ----------
// M=50048 x K=128 x N=256 per half; grid (782, 2), 256 thr / 4 waves,
// wave owns 64 cols of this half. Reuses Bpack: ks 0..3 = W_top, 4..7 = W_bot.
__global__ __launch_bounds__(256, 2) void ygemm_kernel(
    const unsigned short* __restrict__ zb, const unsigned short* __restrict__ Bpack,
    const float* __restrict__ be1, unsigned short* __restrict__ Y)
{
    __shared__ __align__(16) unsigned short s_a[64][136];
    const int tid = threadIdx.x;
    const int lane = tid & 63, w = tid >> 6;
    const int m16 = lane & 15, quad = lane >> 4;
    const int n0 = blockIdx.x * 64;
    const int half = blockIdx.y;

    // stage A: 64 rows x 256B = 1024 16B-chunks, 4/thread
    #pragma unroll
    for (int i = 0; i < 4; ++i) {
        int c = tid + i * 256;
        int row = c >> 4, col = (c & 15) * 8;
        *(uint4*)&s_a[row][col] = *(const uint4*)(zb + (size_t)(n0 + row) * C_IN + col);
    }

    bf16x8 bfr[4][4];
    {
        const bf16x8* bp = (const bf16x8*)Bpack;
        #pragma unroll
        for (int ks = 0; ks < 4; ++ks)
            #pragma unroll
            for (int nt = 0; nt < 4; ++nt)
                bfr[ks][nt] = bp[((half * 4 + ks) * 16 + (w * 4 + nt)) * 64 + lane];
    }
    __syncthreads();

    f32x4 acc[4][4];
    #pragma unroll
    for (int mt = 0; mt < 4; ++mt)
        #pragma unroll
        for (int nt = 0; nt < 4; ++nt)
            acc[mt][nt] = (f32x4){0.f, 0.f, 0.f, 0.f};

    #pragma unroll
    for (int ks = 0; ks < 4; ++ks) {
        #pragma unroll
        for (int mt = 0; mt < 4; ++mt) {
            bf16x8 a = *(const bf16x8*)&s_a[mt * 16 + m16][ks * 32 + quad * 8];
            #pragma unroll
            for (int nt = 0; nt < 4; ++nt)
                acc[mt][nt] = __builtin_amdgcn_mfma_f32_16x16x32_bf16(
                    a, bfr[ks][nt], acc[mt][nt], 0, 0, 0);
        }
    }

    #pragma unroll
    for (int nt = 0; nt < 4; ++nt) {
        const int c = w * 64 + nt * 16 + m16;           // col within half
        const float b = half ? be1[c] : 0.f;
        #pragma unroll
        for (int mt = 0; mt < 4; ++mt)
            #pragma unroll
            for (int r = 0; r < 4; ++r) {
                const int node = n0 + mt * 16 + quad * 4 + r;
                Y[(size_t)node * YSTRIDE + half * 256 + c] = f2bf(acc[mt][nt][r] + b);
            }
    }
}

// ---------- fused edge elementwise + gather-mean (ONE WAVE per dst node) ----------
// 64-thread blocks: no intra-block degree imbalance, finer scheduling.
// Y_hi[dst] + We2 hoisted to registers once per node. Edge dot: 16 lanes per
// edge x 16 channels per lane; reduce is 4 xor stages on one register per
// 4 edges. CSR records (src, edge_id, attr) arrive as ONE uniform int4 stream,
// software-pipelined one iteration ahead (SGPR scalar loads overlap the
// gather+compute of the current iteration). Edge-attr sum is a uniform
// accumulate — no strided loads, no reduce.
// After the edge loop, segb is written into the node's own Y_hi bytes
// (ch 256..415): this wave already consumed Y_hi[n], and src gathers only
// touch Y_lo, so the in-place overwrite is race-free.
__device__ __forceinline__ float dot8(uint4 q, const float* __restrict__ d,
                                      const float* __restrict__ wv, float p) {
    const unsigned u[4] = {q.x, q.y, q.z, q.w};
    #pragma unroll
    for (int j = 0; j < 4; ++j) {
        const float lo = __uint_as_float(u[j] << 16)         + d[2 * j];
        const float hi = __uint_as_float(u[j] & 0xffff0000u) + d[2 * j + 1];
        p = fmaf(fmaxf(lo, 0.f), wv[2 * j],     p);
        p = fmaf(fmaxf(hi, 0.f), wv[2 * j + 1], p);
    }
    return p;
}

__global__ __launch_bounds__(64, 6) void fused_eg_kernel(
    unsigned short* __restrict__ Y, const unsigned short* __restrict__ zb,
    const int* __restrict__ offsets, const int4* __restrict__ erec,
    const float* __restrict__ We2, const float* __restrict__ be2,
    float* __restrict__ edge_out)
{
    const int lane = threadIdx.x;
    const int n = blockIdx.x;
    const int c = lane & 15, g = lane >> 4;           // 16 lanes per edge-slot
    const int beg = offsets[n], end = offsets[n + 1], deg = end - beg;
    const float be2v = be2[0];

    // hoist dst half-row (ch c*8+0..7 and 128+c*8+0..7) + matching We2
    float d0[8], d1[8], w0[8], w1[8];
    {
        const unsigned short* yh = Y + (size_t)n * YSTRIDE + 256;
        uint4 q0 = *(const uint4*)(yh + c * 8);
        uint4 q1 = *(const uint4*)(yh + 128 + c * 8);
        const unsigned a0[4] = {q0.x, q0.y, q0.z, q0.w};
        const unsigned a1[4] = {q1.x, q1.y, q1.z, q1.w};
        #pragma unroll
        for (int j = 0; j < 4; ++j) {
            d0[2 * j]     = __uint_as_float(a0[j] << 16);
            d0[2 * j + 1] = __uint_as_float(a0[j] & 0xffff0000u);
            d1[2 * j]     = __uint_as_float(a1[j] << 16);
            d1[2 * j + 1] = __uint_as_float(a1[j] & 0xffff0000u);
        }
        #pragma unroll
        for (int j = 0; j < 8; ++j) {
            w0[j] = We2[c * 8 + j];
            w1[j] = We2[128 + c * 8 + j];
        }
    }

    float ax = 0.f, ay = 0.f;                  // lane owns z-channels lane*2, lane*2+1
    float asum = 0.f;                          // uniform across wave
    const int nfull = deg >> 2;
    int i = beg;
    int4 ra, rb, rc, rd;                       // pipelined record prefetch (uniform)
    if (nfull) { ra = erec[i]; rb = erec[i + 1]; rc = erec[i + 2]; rd = erec[i + 3]; }
    for (int it = 0; it < nfull; ++it) {
        const int4 c0 = ra, c1 = rb, c2 = rc, c3 = rd;
        i += 4;
        if (it + 1 < nfull) {
            ra = erec[i]; rb = erec[i + 1]; rc = erec[i + 2]; rd = erec[i + 3];
        }
        asum += __int_as_float(c0.z) + __int_as_float(c1.z)
              + __int_as_float(c2.z) + __int_as_float(c3.z);
        // z-mean: all 64 lanes, all 4 edges
        const unsigned u0 = *(const unsigned*)(zb + (size_t)c0.x * C_IN + lane * 2);
        const unsigned u1 = *(const unsigned*)(zb + (size_t)c1.x * C_IN + lane * 2);
        const unsigned u2 = *(const unsigned*)(zb + (size_t)c2.x * C_IN + lane * 2);
        const unsigned u3 = *(const unsigned*)(zb + (size_t)c3.x * C_IN + lane * 2);
        ax += __uint_as_float(u0 << 16) + __uint_as_float(u1 << 16)
            + __uint_as_float(u2 << 16) + __uint_as_float(u3 << 16);
        ay += __uint_as_float(u0 & 0xffff0000u) + __uint_as_float(u1 & 0xffff0000u)
            + __uint_as_float(u2 & 0xffff0000u) + __uint_as_float(u3 & 0xffff0000u);
        // edge dot: group g owns edge it*4+g
        const int sg = (g == 0) ? c0.x : (g == 1) ? c1.x : (g == 2) ? c2.x : c3.x;
        const int eg = (g == 0) ? c0.y : (g == 1) ? c1.y : (g == 2) ? c2.y : c3.y;
        const unsigned short* yr = Y + (size_t)sg * YSTRIDE;
        const uint4 q0 = *(const uint4*)(yr + c * 8);
        const uint4 q1 = *(const uint4*)(yr + 128 + c * 8);
        float p = dot8(q0, d0, w0, 0.f);
        p = dot8(q1, d1, w1, p);
        p += __shfl_xor(p, 1, 64);
        p += __shfl_xor(p, 2, 64);
        p += __shfl_xor(p, 4, 64);
        p += __shfl_xor(p, 8, 64);
        if (c == 0) edge_out[eg] = p + be2v;
    }
    for (; i < end; ++i) {                     // tail (<=3 edges)
        const int4 r = erec[i];
        asum += __int_as_float(r.z);
        const unsigned u = *(const unsigned*)(zb + (size_t)r.x * C_IN + lane * 2);
        ax += __uint_as_float(u << 16);
        ay += __uint_as_float(u & 0xffff0000u);
        const unsigned short* yr = Y + (size_t)r.x * YSTRIDE;
        const uint4 q0 = *(const uint4*)(yr + c * 8);
        const uint4 q1 = *(const uint4*)(yr + 128 + c * 8);
        float p = dot8(q0, d0, w0, 0.f);
        p = dot8(q1, d1, w1, p);
        p += __shfl_xor(p, 1, 64);
        p += __shfl_xor(p, 2, 64);
        p += __shfl_xor(p, 4, 64);
        p += __shfl_xor(p, 8, 64);
        if (lane == 0) edge_out[r.y] = p + be2v;
    }

    const float inv = (deg > 0) ? 1.0f / (float)deg : 0.0f;
    unsigned short* segn = Y + (size_t)n * YSTRIDE + 256;   // in-place: Y_hi is dead now
    ushort2 o; o.x = f2bf(ax * inv); o.y = f2bf(ay * inv);
    *(ushort2*)(segn + lane * 2) = o;
    if (lane < 16) {
        ushort2 pz; pz.x = (lane == 0) ? f2bf(asum * inv) : (unsigned short)0; pz.y = 0;
        *(ushort2*)(segn + 128 + lane * 2) = pz;   // attr @128, zeros 129..159
    }
}

// ---------- node MLP: bf16 MFMA, both layers, h via LDS round-trip ----------
// segb lives in Y ch 256..415 of each row (stride YSTRIDE).
__global__ __launch_bounds__(256, 2) void node_mfma_kernel(
    const unsigned short* __restrict__ segb, const unsigned short* __restrict__ Wa1b,
    const float* __restrict__ ba1, const unsigned short* __restrict__ Wa2b,
    const float* __restrict__ ba2, float* __restrict__ x_out)
{
    __shared__ __align__(16) unsigned short s_a[64][168];
    __shared__ __align__(16) unsigned short s_h[64][264];
    const int tid  = threadIdx.x;
    const int lane = tid & 63, w = tid >> 6;
    const int m16 = lane & 15, quad = lane >> 4;
    const int n0 = blockIdx.x * 64;

    {
        const unsigned short* src = segb + (size_t)n0 * YSTRIDE + 256;
        #pragma unroll
        for (int i = 0; i < 5; ++i) {
            int c = tid + i * 256;
            int row = c / 20, col = c - row * 20;
            *(uint4*)&s_a[row][col * 8] =
                *(const uint4*)(src + (size_t)row * YSTRIDE + col * 8);
        }
    }

    bf16x8 bfr1[5][4];
    {
        const bf16x8* bp = (const bf16x8*)Wa1b;
        #pragma unroll
        for (int ks = 0; ks < 5; ++ks)
            #pragma unroll
            for (int nt = 0; nt < 4; ++nt)
                bfr1[ks][nt] = bp[(ks * 16 + (w * 4 + nt)) * 64 + lane];
    }
    __syncthreads();

    f32x4 acc1[4][4];
    #pragma unroll
    for (int mt = 0; mt < 4; ++mt)
        #pragma unroll
        for (int nt = 0; nt < 4; ++nt)
            acc1[mt][nt] = (f32x4){0.f, 0.f, 0.f, 0.f};

    #pragma unroll
    for (int ks = 0; ks < 5; ++ks) {
        #pragma unroll
        for (int mt = 0; mt < 4; ++mt) {
            bf16x8 a = *(const bf16x8*)&s_a[mt * 16 + m16][ks * 32 + quad * 8];
            #pragma unroll
            for (int nt = 0; nt < 4; ++nt)
                acc1[mt][nt] = __builtin_amdgcn_mfma_f32_16x16x32_bf16(
                    a, bfr1[ks][nt], acc1[mt][nt], 0, 0, 0);
        }
    }

    #pragma unroll
    for (int nt = 0; nt < 4; ++nt) {
        const int chan = w * 64 + nt * 16 + m16;
        const float b1 = ba1[chan];
        #pragma unroll
        for (int mt = 0; mt < 4; ++mt)
            #pragma unroll
            for (int r = 0; r < 4; ++r) {
                const int node = mt * 16 + quad * 4 + r;
                s_h[node][chan] = f2bf(fmaxf(acc1[mt][nt][r] + b1, 0.f));
            }
    }

    bf16x8 bfr2[8][2];
    {
        const bf16x8* bp = (const bf16x8*)Wa2b;
        #pragma unroll
        for (int ks = 0; ks < 8; ++ks)
            #pragma unroll
            for (int nt = 0; nt < 2; ++nt)
                bfr2[ks][nt] = bp[(ks * 8 + (w * 2 + nt)) * 64 + lane];
    }
    __syncthreads();

    f32x4 acc2[4][2];
    #pragma unroll
    for (int mt = 0; mt < 4; ++mt)
        #pragma unroll
        for (int nt = 0; nt < 2; ++nt)
            acc2[mt][nt] = (f32x4){0.f, 0.f, 0.f, 0.f};

    #pragma unroll
    for (int ks = 0; ks < 8; ++ks) {
        #pragma unroll
        for (int mt = 0; mt < 4; ++mt) {
            bf16x8 a = *(const bf16x8*)&s_h[mt * 16 + m16][ks * 32 + quad * 8];
            #pragma unroll
            for (int nt = 0; nt < 2; ++nt)
                acc2[mt][nt] = __builtin_amdgcn_mfma_f32_16x16x32_bf16(
                    a, bfr2[ks][nt], acc2[mt][nt], 0, 0, 0);
        }
    }

    #pragma unroll
    for (int nt = 0; nt < 2; ++nt) {
        const int j = w * 32 + nt * 16 + m16;
        const float b2 = ba2[j];
        #pragma unroll
        for (int mt = 0; mt < 4; ++mt)
            #pragma unroll
            for (int r = 0; r < 4; ++r) {
                const int node = n0 + mt * 16 + quad * 4 + r;
                if (node < N_NODES)
                    x_out[(size_t)node * C_OUT + j] = acc2[mt][nt][r] + b2;
            }
    }
}

// ---------- launch ----------
// ws layout (bytes), total ~77.5 MB:
//   Y       51,249,152   (50048 x 512 bf16; ch 256..415 become segb in-place)
//   zb      12,812,288   (50048 rows; 50000 valid, tail garbage never used)
//   Bpack      131,072
//   Wa1b        81,920
//   Wa2b        65,536
//   cnt        200,704   (50176 ints, zero-padded for int4 scan; consumed by fill)
//   offsets    200,064
//   erec    12,800,000   (800000 x int4 {src, edge_id, attr_bits, 0})

extern "C" void kernel_launch(void* const* d_in, const int* in_sizes, int n_in,
                              void* d_out, int out_size, void* d_ws, size_t ws_size,
                              hipStream_t stream) {
    const float* z     = (const float*)d_in[0];
    const int*   ei    = (const int*)d_in[1];     // int32 per harness contract
    const float* eattr = (const float*)d_in[2];
    const float* Wa1   = (const float*)d_in[3];
    const float* ba1   = (const float*)d_in[4];
    const float* Wa2   = (const float*)d_in[5];
    const float* ba2   = (const float*)d_in[6];
    const float* We1   = (const float*)d_in[7];
    const float* be1   = (const float*)d_in[8];
    const float* We2   = (const float*)d_in[9];
    const float* be2   = (const float*)d_in[10];

    float* x_out    = (float*)d_out;
    float* edge_out = x_out + (size_t)N_NODES * C_OUT;

    char* wsb = (char*)d_ws;
    size_t off = 0;
    unsigned short* Y       = (unsigned short*)(wsb + off); off += 51249152;
    unsigned short* zb      = (unsigned short*)(wsb + off); off += 12812288;
    unsigned short* Bpack   = (unsigned short*)(wsb + off); off += 131072;
    unsigned short* Wa1b    = (unsigned short*)(wsb + off); off += 81920;
    unsigned short* Wa2b    = (unsigned short*)(wsb + off); off += 65536;
    int*            cnt     = (int*)(wsb + off);            off += 200704;
    int*            offsets = (int*)(wsb + off);            off += 200064;
    int4*           erec    = (int4*)(wsb + off);           off += 12800000;

    hipMemsetAsync(cnt, 0, 200704, stream);

    prep_kernel<<<6250 + 3125 + 32 + 20 + 16, 256, 0, stream>>>(
        z, ei, We1, Wa1, Wa2, zb, cnt, Bpack, Wa1b, Wa2b);

    scan_kernel<<<1, 256, 0, stream>>>(cnt, offsets);
    fill_kernel<<<(N_EDGES + 255) / 256, 256, 0, stream>>>(ei, eattr, offsets, cnt,
                                                           erec);

    ygemm_kernel<<<dim3(782, 2), 256, 0, stream>>>(zb, Bpack, be1, Y);

    fused_eg_kernel<<<N_NODES, 64, 0, stream>>>(
        Y, zb, offsets, erec, We2, be2, edge_out);

    node_mfma_kernel<<<(N_NODES + 63) / 64, 256, 0, stream>>>(Y, Wa1b, ba1, Wa2b,
                                                              ba2, x_out);
}

// Round 3
// 361.843 us; speedup vs baseline: 1.1662x; 1.0795x over previous
//
#include <hip/hip_runtime.h>

#define N_NODES 50000
#define N_EDGES 800000
#define C_IN    128
#define C_HID   256
#define C_OUT   128
#define YSTRIDE 512       // bf16: [y_src 0..255 | y_dst 256..511]; after fused kernel,
                          // ch 256..415 of each row are overwritten with segb
                          // [z-mean 0..127 | attr 128 | zeros 129..159]

typedef __bf16 bf16x8 __attribute__((ext_vector_type(8)));
typedef float  f32x4  __attribute__((ext_vector_type(4)));

__device__ __forceinline__ unsigned short f2bf(float x) {
    unsigned u = __float_as_uint(x);
    u = (u + 0x7FFF + ((u >> 16) & 1)) >> 16;   // RNE
    return (unsigned short)u;
}

// ---------- fused prep: cast_z | hist | bpack | wa1b | wa2b ----------
__global__ __launch_bounds__(256) void prep_kernel(
    const float* __restrict__ z, const int* __restrict__ ei,
    const float* __restrict__ We1, const float* __restrict__ Wa1,
    const float* __restrict__ Wa2,
    unsigned short* __restrict__ zb, int* __restrict__ cnt,
    unsigned short* __restrict__ Bpack, unsigned short* __restrict__ Wa1b,
    unsigned short* __restrict__ Wa2b)
{
    const int b = blockIdx.x;
    const int tid = threadIdx.x;
    if (b < 6250) {                                   // cast_z: 6250*256 = 1.6M float4
        int t = b * 256 + tid;
        float4 v = ((const float4*)z)[t];
        ushort4 o;
        o.x = f2bf(v.x); o.y = f2bf(v.y); o.z = f2bf(v.z); o.w = f2bf(v.w);
        ((ushort4*)zb)[t] = o;
    } else if (b < 6250 + 3125) {                     // hist: 3125*256 = 800000
        int e = (b - 6250) * 256 + tid;
        atomicAdd(&cnt[ei[N_EDGES + e]], 1);
    } else if (b < 6250 + 3125 + 32) {                // Bpack (We1 B-frags, 8ks x 16nt)
        int t = (b - 6250 - 3125) * 256 + tid;        // 8192 lane-slots
        int lane = t & 63, nt = (t >> 6) & 15, ks = t >> 10;
        int n  = nt * 16 + (lane & 15);
        int kb = ks * 32 + (lane >> 4) * 8;
        #pragma unroll
        for (int j = 0; j < 8; ++j)
            Bpack[t * 8 + j] = f2bf(We1[(kb + j) * C_HID + n]);
    } else if (b < 6250 + 3125 + 32 + 20) {           // Wa1b (node layer1)
        int t = (b - 6250 - 3125 - 32) * 256 + tid;
        if (t >= 5 * 16 * 64) return;
        int lane = t & 63, nt = (t >> 6) & 15, ks = t >> 10;
        int n = nt * 16 + (lane & 15);
        #pragma unroll
        for (int j = 0; j < 8; ++j) {
            int k = ks * 32 + (lane >> 4) * 8 + j;
            float v = 0.f;
            if (k < 128)       v = Wa1[(k + 1) * C_HID + n];
            else if (k == 128) v = Wa1[0 * C_HID + n];
            Wa1b[t * 8 + j] = f2bf(v);
        }
    } else {                                          // Wa2b (node layer2)
        int t = (b - 6250 - 3125 - 32 - 20) * 256 + tid;
        if (t >= 8 * 8 * 64) return;
        int lane = t & 63, nt = (t >> 6) & 7, ks = t >> 9;
        int n  = nt * 16 + (lane & 15);
        int kb = ks * 32 + (lane >> 4) * 8;
        #pragma unroll
        for (int j = 0; j < 8; ++j)
            Wa2b[t * 8 + j] = f2bf(Wa2[(kb + j) * C_OUT + n]);
    }
}

// ---------- CSR scan (single block; offsets rebuilt with int4 running prefix) ----------
// cnt zero-padded to 50176 ints; offsets buffer padded to 50176 ints so the
// vectorized stores need no bounds checks (entries >50000 are garbage, unused;
// offsets[50000] lands correctly since cnt[50000..] == 0).
// 196*4 B = 49*16 B, so per-thread int4 base is 16-B aligned.
__global__ __launch_bounds__(256) void scan_kernel(const int* __restrict__ cnt,
                                                   int* __restrict__ offsets) {
    const int tid = threadIdx.x;
    const int base = tid * 196;                 // 49 int4 per thread
    const int4* c4 = (const int4*)(cnt + base);
    int sum = 0;
    #pragma unroll 7
    for (int i = 0; i < 49; ++i) {
        int4 v = c4[i];
        sum += v.x + v.y + v.z + v.w;
    }
    const int lane = tid & 63, w = tid >> 6;
    int v = sum;
    #pragma unroll
    for (int off = 1; off < 64; off <<= 1) {
        int t = __shfl_up(v, off, 64);
        if (lane >= off) v += t;
    }
    __shared__ int s_w[4];
    if (lane == 63) s_w[w] = v;
    __syncthreads();
    int wbase = 0;
    for (int i = 0; i < w; ++i) wbase += s_w[i];
    int run = wbase + v - sum;
    int4* o4 = (int4*)(offsets + base);
    #pragma unroll 7
    for (int i = 0; i < 49; ++i) {
        int4 cv = c4[i];                        // L1/L2-hot reload
        int4 o;
        o.x = run; run += cv.x;
        o.y = run; run += cv.y;
        o.z = run; run += cv.z;
        o.w = run; run += cv.w;
        o4[i] = o;
    }
}

// ---------- merged fill + Y GEMM (independent work, one launch to overlap) ----------
// Blocks 0..3124: fill — one scattered 16-B erec store per edge; slot via
//   atomicSub on cnt (cnt is dead after scan).
// Blocks 3125..4688: ygemm — Y[:,0:256] = zb@We1_top ; Y[:,256:512] = zb@We1_bot+be1.
//   M=50048 x K=128 x N=256 per half; wave owns 64 cols of its half.
__global__ __launch_bounds__(256, 2) void fy_kernel(
    const int* __restrict__ ei, const float* __restrict__ eattr,
    const int* __restrict__ offsets, int* __restrict__ cnt, int4* __restrict__ erec,
    const unsigned short* __restrict__ zb, const unsigned short* __restrict__ Bpack,
    const float* __restrict__ be1, unsigned short* __restrict__ Y)
{
    const int tid = threadIdx.x;
    if (blockIdx.x < 3125) {                          // ---- fill ----
        int e = blockIdx.x * 256 + tid;
        int d = ei[N_EDGES + e];
        int pos = atomicSub(&cnt[d], 1) - 1;
        erec[offsets[d] + pos] = make_int4(ei[e], e, __float_as_int(eattr[e]), 0);
        return;
    }
    // ---- ygemm ----
    __shared__ __align__(16) unsigned short s_a[64][136];
    const int yb = blockIdx.x - 3125;                 // 0..1563
    const int n0 = (yb >> 1) * 64;
    const int half = yb & 1;
    const int lane = tid & 63, w = tid >> 6;
    const int m16 = lane & 15, quad = lane >> 4;

    // stage A: 64 rows x 256B = 1024 16B-chunks, 4/thread
    #pragma unroll
    for (int i = 0; i < 4; ++i) {
        int c = tid + i * 256;
        int row = c >> 4, col = (c & 15) * 8;
        *(uint4*)&s_a[row][col] = *(const uint4*)(zb + (size_t)(n0 + row) * C_IN + col);
    }

    bf16x8 bfr[4][4];
    {
        const bf16x8* bp = (const bf16x8*)Bpack;
        #pragma unroll
        for (int ks = 0; ks < 4; ++ks)
            #pragma unroll
            for (int nt = 0; nt < 4; ++nt)
                bfr[ks][nt] = bp[((half * 4 + ks) * 16 + (w * 4 + nt)) * 64 + lane];
    }
    __syncthreads();

    f32x4 acc[4][4];
    #pragma unroll
    for (int mt = 0; mt < 4; ++mt)
        #pragma unroll
        for (int nt = 0; nt < 4; ++nt)
            acc[mt][nt] = (f32x4){0.f, 0.f, 0.f, 0.f};

    #pragma unroll
    for (int ks = 0; ks < 4; ++ks) {
        #pragma unroll
        for (int mt = 0; mt < 4; ++mt) {
            bf16x8 a = *(const bf16x8*)&s_a[mt * 16 + m16][ks * 32 + quad * 8];
            #pragma unroll
            for (int nt = 0; nt < 4; ++nt)
                acc[mt][nt] = __builtin_amdgcn_mfma_f32_16x16x32_bf16(
                    a, bfr[ks][nt], acc[mt][nt], 0, 0, 0);
        }
    }

    #pragma unroll
    for (int nt = 0; nt < 4; ++nt) {
        const int c = w * 64 + nt * 16 + m16;           // col within half
        const float b = half ? be1[c] : 0.f;
        #pragma unroll
        for (int mt = 0; mt < 4; ++mt)
            #pragma unroll
            for (int r = 0; r < 4; ++r) {
                const int node = n0 + mt * 16 + quad * 4 + r;
                Y[(size_t)node * YSTRIDE + half * 256 + c] = f2bf(acc[mt][nt][r] + b);
            }
    }
}

// ---------- fused edge elementwise + gather-mean (one wave per dst node) ----------
// 128-thread blocks = 2 independent waves (occupancy: 1-wave WGs were
// workgroup-slot limited at 68%). Y_hi[dst] + We2 hoisted to registers once
// per node. Edge dot: 16 lanes per edge x 16 channels per lane; 4-stage xor
// reduce. DOUBLE-BUFFERED: records AND gathers (zb row + Y_lo row) for
// group t+1 are issued while computing group t, hiding the L2/L3 round trip.
// segb is written in-place into the node's own Y_hi bytes (ch 256..415):
// this wave already consumed Y_hi[n]; src gathers touch Y_lo only.
__device__ __forceinline__ float dot8(uint4 q, const float* __restrict__ d,
                                      const float* __restrict__ wv, float p) {
    const unsigned u[4] = {q.x, q.y, q.z, q.w};
    #pragma unroll
    for (int j = 0; j < 4; ++j) {
        const float lo = __uint_as_float(u[j] << 16)         + d[2 * j];
        const float hi = __uint_as_float(u[j] & 0xffff0000u) + d[2 * j + 1];
        p = fmaf(fmaxf(lo, 0.f), wv[2 * j],     p);
        p = fmaf(fmaxf(hi, 0.f), wv[2 * j + 1], p);
    }
    return p;
}

__global__ __launch_bounds__(128) void fused_eg_kernel(
    unsigned short* __restrict__ Y, const unsigned short* __restrict__ zb,
    const int* __restrict__ offsets, const int4* __restrict__ erec,
    const float* __restrict__ We2, const float* __restrict__ be2,
    float* __restrict__ edge_out)
{
    const int lane = threadIdx.x & 63;
    const int n = blockIdx.x * 2 + (threadIdx.x >> 6);   // grid 25000 x 2 waves = 50000
    const int c = lane & 15, g = lane >> 4;              // 16 lanes per edge-slot
    const int beg = offsets[n], end = offsets[n + 1], deg = end - beg;
    const float be2v = be2[0];

    // hoist dst half-row (ch c*8+0..7 and 128+c*8+0..7) + matching We2
    float d0[8], d1[8], w0[8], w1[8];
    {
        const unsigned short* yh = Y + (size_t)n * YSTRIDE + 256;
        uint4 q0 = *(const uint4*)(yh + c * 8);
        uint4 q1 = *(const uint4*)(yh + 128 + c * 8);
        const unsigned a0[4] = {q0.x, q0.y, q0.z, q0.w};
        const unsigned a1[4] = {q1.x, q1.y, q1.z, q1.w};
        #pragma unroll
        for (int j = 0; j < 4; ++j) {
            d0[2 * j]     = __uint_as_float(a0[j] << 16);
            d0[2 * j + 1] = __uint_as_float(a0[j] & 0xffff0000u);
            d1[2 * j]     = __uint_as_float(a1[j] << 16);
            d1[2 * j + 1] = __uint_as_float(a1[j] & 0xffff0000u);
        }
        #pragma unroll
        for (int j = 0; j < 8; ++j) {
            w0[j] = We2[c * 8 + j];
            w1[j] = We2[128 + c * 8 + j];
        }
    }

    float ax = 0.f, ay = 0.f;                  // lane owns z-channels lane*2, lane*2+1
    float asum = 0.f;                          // uniform across wave
    const int nfull = deg >> 2;
    int i = beg;

    int4 cr0, cr1, cr2, cr3;                   // current records (SGPR)
    unsigned cu0, cu1, cu2, cu3;               // current zb gathers
    uint4 cq0, cq1;                            // current Y_lo gathers
    if (nfull) {
        cr0 = erec[i]; cr1 = erec[i + 1]; cr2 = erec[i + 2]; cr3 = erec[i + 3];
        cu0 = *(const unsigned*)(zb + (size_t)cr0.x * C_IN + lane * 2);
        cu1 = *(const unsigned*)(zb + (size_t)cr1.x * C_IN + lane * 2);
        cu2 = *(const unsigned*)(zb + (size_t)cr2.x * C_IN + lane * 2);
        cu3 = *(const unsigned*)(zb + (size_t)cr3.x * C_IN + lane * 2);
        const int sg = (g == 0) ? cr0.x : (g == 1) ? cr1.x : (g == 2) ? cr2.x : cr3.x;
        const unsigned short* yr = Y + (size_t)sg * YSTRIDE;
        cq0 = *(const uint4*)(yr + c * 8);
        cq1 = *(const uint4*)(yr + 128 + c * 8);
    }
    for (int it = 0; it < nfull; ++it) {
        i += 4;
        int4 nr0, nr1, nr2, nr3;
        unsigned nu0, nu1, nu2, nu3;
        uint4 nq0, nq1;
        if (it + 1 < nfull) {                  // prefetch group it+1 (records + gathers)
            nr0 = erec[i]; nr1 = erec[i + 1]; nr2 = erec[i + 2]; nr3 = erec[i + 3];
            nu0 = *(const unsigned*)(zb + (size_t)nr0.x * C_IN + lane * 2);
            nu1 = *(const unsigned*)(zb + (size_t)nr1.x * C_IN + lane * 2);
            nu2 = *(const unsigned*)(zb + (size_t)nr2.x * C_IN + lane * 2);
            nu3 = *(const unsigned*)(zb + (size_t)nr3.x * C_IN + lane * 2);
            const int sg = (g == 0) ? nr0.x : (g == 1) ? nr1.x : (g == 2) ? nr2.x : nr3.x;
            const unsigned short* yr = Y + (size_t)sg * YSTRIDE;
            nq0 = *(const uint4*)(yr + c * 8);
            nq1 = *(const uint4*)(yr + 128 + c * 8);
        }
        // ---- compute on current group ----
        asum += __int_as_float(cr0.z) + __int_as_float(cr1.z)
              + __int_as_float(cr2.z) + __int_as_float(cr3.z);
        ax += __uint_as_float(cu0 << 16) + __uint_as_float(cu1 << 16)
            + __uint_as_float(cu2 << 16) + __uint_as_float(cu3 << 16);
        ay += __uint_as_float(cu0 & 0xffff0000u) + __uint_as_float(cu1 & 0xffff0000u)
            + __uint_as_float(cu2 & 0xffff0000u) + __uint_as_float(cu3 & 0xffff0000u);
        const int eg = (g == 0) ? cr0.y : (g == 1) ? cr1.y : (g == 2) ? cr2.y : cr3.y;
        float p = dot8(cq0, d0, w0, 0.f);
        p = dot8(cq1, d1, w1, p);
        p += __shfl_xor(p, 1, 64);
        p += __shfl_xor(p, 2, 64);
        p += __shfl_xor(p, 4, 64);
        p += __shfl_xor(p, 8, 64);
        if (c == 0) edge_out[eg] = p + be2v;
        // rotate buffers
        cr0 = nr0; cr1 = nr1; cr2 = nr2; cr3 = nr3;
        cu0 = nu0; cu1 = nu1; cu2 = nu2; cu3 = nu3;
        cq0 = nq0; cq1 = nq1;
    }
    for (; i < end; ++i) {                     // tail (<=3 edges)
        const int4 r = erec[i];
        asum += __int_as_float(r.z);
        const unsigned u = *(const unsigned*)(zb + (size_t)r.x * C_IN + lane * 2);
        ax += __uint_as_float(u << 16);
        ay += __uint_as_float(u & 0xffff0000u);
        const unsigned short* yr = Y + (size_t)r.x * YSTRIDE;
        const uint4 q0 = *(const uint4*)(yr + c * 8);
        const uint4 q1 = *(const uint4*)(yr + 128 + c * 8);
        float p = dot8(q0, d0, w0, 0.f);
        p = dot8(q1, d1, w1, p);
        p += __shfl_xor(p, 1, 64);
        p += __shfl_xor(p, 2, 64);
        p += __shfl_xor(p, 4, 64);
        p += __shfl_xor(p, 8, 64);
        if (lane == 0) edge_out[r.y] = p + be2v;
    }

    const float inv = (deg > 0) ? 1.0f / (float)deg : 0.0f;
    unsigned short* segn = Y + (size_t)n * YSTRIDE + 256;   // in-place: Y_hi is dead now
    ushort2 o; o.x = f2bf(ax * inv); o.y = f2bf(ay * inv);
    *(ushort2*)(segn + lane * 2) = o;
    if (lane < 16) {
        ushort2 pz; pz.x = (lane == 0) ? f2bf(asum * inv) : (unsigned short)0; pz.y = 0;
        *(ushort2*)(segn + 128 + lane * 2) = pz;   // attr @128, zeros 129..159
    }
}

// ---------- node MLP: bf16 MFMA, both layers, h via LDS round-trip ----------
// segb lives in Y ch 256..415 of each row (stride YSTRIDE).
__global__ __launch_bounds__(256, 2) void node_mfma_kernel(
    const unsigned short* __restrict__ segb, const unsigned short* __restrict__ Wa1b,
    const float* __restrict__ ba1, const unsigned short* __restrict__ Wa2b,
    const float* __restrict__ ba2, float* __restrict__ x_out)
{
    __shared__ __align__(16) unsigned short s_a[64][168];
    __shared__ __align__(16) unsigned short s_h[64][264];
    const int tid  = threadIdx.x;
    const int lane = tid & 63, w = tid >> 6;
    const int m16 = lane & 15, quad = lane >> 4;
    const int n0 = blockIdx.x * 64;

    {
        const unsigned short* src = segb + (size_t)n0 * YSTRIDE + 256;
        #pragma unroll
        for (int i = 0; i < 5; ++i) {
            int c = tid + i * 256;
            int row = c / 20, col = c - row * 20;
            *(uint4*)&s_a[row][col * 8] =
                *(const uint4*)(src + (size_t)row * YSTRIDE + col * 8);
        }
    }

    bf16x8 bfr1[5][4];
    {
        const bf16x8* bp = (const bf16x8*)Wa1b;
        #pragma unroll
        for (int ks = 0; ks < 5; ++ks)
            #pragma unroll
            for (int nt = 0; nt < 4; ++nt)
                bfr1[ks][nt] = bp[(ks * 16 + (w * 4 + nt)) * 64 + lane];
    }
    __syncthreads();

    f32x4 acc1[4][4];
    #pragma unroll
    for (int mt = 0; mt < 4; ++mt)
        #pragma unroll
        for (int nt = 0; nt < 4; ++nt)
            acc1[mt][nt] = (f32x4){0.f, 0.f, 0.f, 0.f};

    #pragma unroll
    for (int ks = 0; ks < 5; ++ks) {
        #pragma unroll
        for (int mt = 0; mt < 4; ++mt) {
            bf16x8 a = *(const bf16x8*)&s_a[mt * 16 + m16][ks * 32 + quad * 8];
            #pragma unroll
            for (int nt = 0; nt < 4; ++nt)
                acc1[mt][nt] = __builtin_amdgcn_mfma_f32_16x16x32_bf16(
                    a, bfr1[ks][nt], acc1[mt][nt], 0, 0, 0);
        }
    }

    #pragma unroll
    for (int nt = 0; nt < 4; ++nt) {
        const int chan = w * 64 + nt * 16 + m16;
        const float b1 = ba1[chan];
        #pragma unroll
        for (int mt = 0; mt < 4; ++mt)
            #pragma unroll
            for (int r = 0; r < 4; ++r) {
                const int node = mt * 16 + quad * 4 + r;
                s_h[node][chan] = f2bf(fmaxf(acc1[mt][nt][r] + b1, 0.f));
            }
    }

    bf16x8 bfr2[8][2];
    {
        const bf16x8* bp = (const bf16x8*)Wa2b;
        #pragma unroll
        for (int ks = 0; ks < 8; ++ks)
            #pragma unroll
            for (int nt = 0; nt < 2; ++nt)
                bfr2[ks][nt] = bp[(ks * 8 + (w * 2 + nt)) * 64 + lane];
    }
    __syncthreads();

    f32x4 acc2[4][2];
    #pragma unroll
    for (int mt = 0; mt < 4; ++mt)
        #pragma unroll
        for (int nt = 0; nt < 2; ++nt)
            acc2[mt][nt] = (f32x4){0.f, 0.f, 0.f, 0.f};

    #pragma unroll
    for (int ks = 0; ks < 8; ++ks) {
        #pragma unroll
        for (int mt = 0; mt < 4; ++mt) {
            bf16x8 a = *(const bf16x8*)&s_h[mt * 16 + m16][ks * 32 + quad * 8];
            #pragma unroll
            for (int nt = 0; nt < 2; ++nt)
                acc2[mt][nt] = __builtin_amdgcn_mfma_f32_16x16x32_bf16(
                    a, bfr2[ks][nt], acc2[mt][nt], 0, 0, 0);
        }
    }

    #pragma unroll
    for (int nt = 0; nt < 2; ++nt) {
        const int j = w * 32 + nt * 16 + m16;
        const float b2 = ba2[j];
        #pragma unroll
        for (int mt = 0; mt < 4; ++mt)
            #pragma unroll
            for (int r = 0; r < 4; ++r) {
                const int node = n0 + mt * 16 + quad * 4 + r;
                if (node < N_NODES)
                    x_out[(size_t)node * C_OUT + j] = acc2[mt][nt][r] + b2;
            }
    }
}

// ---------- launch ----------
// ws layout (bytes), total ~77.6 MB:
//   Y       51,249,152   (50048 x 512 bf16; ch 256..415 become segb in-place)
//   zb      12,812,288   (50048 rows; 50000 valid, tail garbage never used)
//   Bpack      131,072
//   Wa1b        81,920
//   Wa2b        65,536
//   cnt        200,704   (50176 ints, zero-padded for int4 scan; consumed by fill)
//   offsets    200,704   (padded to 50176 ints for vectorized scan stores)
//   erec    12,800,000   (800000 x int4 {src, edge_id, attr_bits, 0})

extern "C" void kernel_launch(void* const* d_in, const int* in_sizes, int n_in,
                              void* d_out, int out_size, void* d_ws, size_t ws_size,
                              hipStream_t stream) {
    const float* z     = (const float*)d_in[0];
    const int*   ei    = (const int*)d_in[1];     // int32 per harness contract
    const float* eattr = (const float*)d_in[2];
    const float* Wa1   = (const float*)d_in[3];
    const float* ba1   = (const float*)d_in[4];
    const float* Wa2   = (const float*)d_in[5];
    const float* ba2   = (const float*)d_in[6];
    const float* We1   = (const float*)d_in[7];
    const float* be1   = (const float*)d_in[8];
    const float* We2   = (const float*)d_in[9];
    const float* be2   = (const float*)d_in[10];

    float* x_out    = (float*)d_out;
    float* edge_out = x_out + (size_t)N_NODES * C_OUT;

    char* wsb = (char*)d_ws;
    size_t off = 0;
    unsigned short* Y       = (unsigned short*)(wsb + off); off += 51249152;
    unsigned short* zb      = (unsigned short*)(wsb + off); off += 12812288;
    unsigned short* Bpack   = (unsigned short*)(wsb + off); off += 131072;
    unsigned short* Wa1b    = (unsigned short*)(wsb + off); off += 81920;
    unsigned short* Wa2b    = (unsigned short*)(wsb + off); off += 65536;
    int*            cnt     = (int*)(wsb + off);            off += 200704;
    int*            offsets = (int*)(wsb + off);            off += 200704;
    int4*           erec    = (int4*)(wsb + off);           off += 12800000;

    hipMemsetAsync(cnt, 0, 200704, stream);

    prep_kernel<<<6250 + 3125 + 32 + 20 + 16, 256, 0, stream>>>(
        z, ei, We1, Wa1, Wa2, zb, cnt, Bpack, Wa1b, Wa2b);

    scan_kernel<<<1, 256, 0, stream>>>(cnt, offsets);

    fy_kernel<<<3125 + 1564, 256, 0, stream>>>(ei, eattr, offsets, cnt, erec,
                                               zb, Bpack, be1, Y);

    fused_eg_kernel<<<N_NODES / 2, 128, 0, stream>>>(
        Y, zb, offsets, erec, We2, be2, edge_out);

    node_mfma_kernel<<<(N_NODES + 63) / 64, 256, 0, stream>>>(Y, Wa1b, ba1, Wa2b,
                                                              ba2, x_out);
}

// Round 4
// 351.688 us; speedup vs baseline: 1.1999x; 1.0289x over previous
//
#include <hip/hip_runtime.h>

#define N_NODES 50000
#define N_EDGES 800000
#define C_IN    128
#define C_HID   256
#define C_OUT   128
#define YSTRIDE 512       // bf16: [y_src 0..255 | y_dst 256..511]; after fused kernel,
                          // ch 256..415 of each row are overwritten with segb
                          // [z-mean 0..127 | attr 128 | zeros 129..159]

typedef __bf16 bf16x8 __attribute__((ext_vector_type(8)));
typedef float  f32x4  __attribute__((ext_vector_type(4)));

__device__ __forceinline__ unsigned short f2bf(float x) {
    unsigned u = __float_as_uint(x);
    u = (u + 0x7FFF + ((u >> 16) & 1)) >> 16;   // RNE
    return (unsigned short)u;
}

// ---------- fused prep: cast_z | hist | bpack | wa1b | wa2b ----------
__global__ __launch_bounds__(256) void prep_kernel(
    const float* __restrict__ z, const int* __restrict__ ei,
    const float* __restrict__ We1, const float* __restrict__ Wa1,
    const float* __restrict__ Wa2,
    unsigned short* __restrict__ zb, int* __restrict__ cnt,
    unsigned short* __restrict__ Bpack, unsigned short* __restrict__ Wa1b,
    unsigned short* __restrict__ Wa2b)
{
    const int b = blockIdx.x;
    const int tid = threadIdx.x;
    if (b < 6250) {                                   // cast_z: 6250*256 = 1.6M float4
        int t = b * 256 + tid;
        float4 v = ((const float4*)z)[t];
        ushort4 o;
        o.x = f2bf(v.x); o.y = f2bf(v.y); o.z = f2bf(v.z); o.w = f2bf(v.w);
        ((ushort4*)zb)[t] = o;
    } else if (b < 6250 + 3125) {                     // hist: 3125*256 = 800000
        int e = (b - 6250) * 256 + tid;
        atomicAdd(&cnt[ei[N_EDGES + e]], 1);
    } else if (b < 6250 + 3125 + 32) {                // Bpack (We1 B-frags, 8ks x 16nt)
        int t = (b - 6250 - 3125) * 256 + tid;        // 8192 lane-slots
        int lane = t & 63, nt = (t >> 6) & 15, ks = t >> 10;
        int n  = nt * 16 + (lane & 15);
        int kb = ks * 32 + (lane >> 4) * 8;
        #pragma unroll
        for (int j = 0; j < 8; ++j)
            Bpack[t * 8 + j] = f2bf(We1[(kb + j) * C_HID + n]);
    } else if (b < 6250 + 3125 + 32 + 20) {           // Wa1b (node layer1)
        int t = (b - 6250 - 3125 - 32) * 256 + tid;
        if (t >= 5 * 16 * 64) return;
        int lane = t & 63, nt = (t >> 6) & 15, ks = t >> 10;
        int n = nt * 16 + (lane & 15);
        #pragma unroll
        for (int j = 0; j < 8; ++j) {
            int k = ks * 32 + (lane >> 4) * 8 + j;
            float v = 0.f;
            if (k < 128)       v = Wa1[(k + 1) * C_HID + n];
            else if (k == 128) v = Wa1[0 * C_HID + n];
            Wa1b[t * 8 + j] = f2bf(v);
        }
    } else {                                          // Wa2b (node layer2)
        int t = (b - 6250 - 3125 - 32 - 20) * 256 + tid;
        if (t >= 8 * 8 * 64) return;
        int lane = t & 63, nt = (t >> 6) & 7, ks = t >> 9;
        int n  = nt * 16 + (lane & 15);
        int kb = ks * 32 + (lane >> 4) * 8;
        #pragma unroll
        for (int j = 0; j < 8; ++j)
            Wa2b[t * 8 + j] = f2bf(Wa2[(kb + j) * C_OUT + n]);
    }
}

// ---------- CSR scan: 1024 threads, 49 ints/thread (1024*49 = 50176 exact) ----------
// cnt zero-padded to 50176; offsets padded to 50176. offsets[50000] lands
// correctly (cnt[50000..] == 0 so the running prefix is total edges there).
__global__ __launch_bounds__(1024) void scan_kernel(const int* __restrict__ cnt,
                                                    int* __restrict__ offsets) {
    const int tid = threadIdx.x;
    const int base = tid * 49;
    int c[49];
    int sum = 0;
    #pragma unroll
    for (int i = 0; i < 49; ++i) { c[i] = cnt[base + i]; sum += c[i]; }
    const int lane = tid & 63, w = tid >> 6;          // 16 waves
    int v = sum;
    #pragma unroll
    for (int off = 1; off < 64; off <<= 1) {
        int t = __shfl_up(v, off, 64);
        if (lane >= off) v += t;
    }
    __shared__ int s_w[16];
    if (lane == 63) s_w[w] = v;
    __syncthreads();
    int wbase = 0;
    #pragma unroll
    for (int i = 0; i < 16; ++i) wbase += (i < w) ? s_w[i] : 0;
    int run = wbase + v - sum;
    #pragma unroll
    for (int i = 0; i < 49; ++i) { offsets[base + i] = run; run += c[i]; }
}

// ---------- merged Y GEMM + fill (ygemm blocks FIRST so long MFMA blocks ----------
// flood the CUs immediately; short scatter fill blocks stream into freed slots).
// Blocks 0..1563: ygemm — Y[:,0:256] = zb@We1_top ; Y[:,256:512] = zb@We1_bot+be1.
//   M=50048 x K=128 x N=256 per half; wave owns 64 cols of its half.
// Blocks 1564..4688: fill — one scattered 8-B int2 record {src, edge_id} per
//   edge (slot via atomicSub on cnt, dead after scan) + float atomicAdd of
//   edge_attr into attr_sum[dst] (so fused_eg reads one value, not E values).
__global__ __launch_bounds__(256, 2) void fy_kernel(
    const int* __restrict__ ei, const float* __restrict__ eattr,
    const int* __restrict__ offsets, int* __restrict__ cnt, int2* __restrict__ erec,
    float* __restrict__ attr_sum,
    const unsigned short* __restrict__ zb, const unsigned short* __restrict__ Bpack,
    const float* __restrict__ be1, unsigned short* __restrict__ Y)
{
    const int tid = threadIdx.x;
    if (blockIdx.x >= 1564) {                         // ---- fill ----
        int e = (blockIdx.x - 1564) * 256 + tid;      // 3125*256 = 800000 exact
        int d = ei[N_EDGES + e];
        int pos = atomicSub(&cnt[d], 1) - 1;
        erec[offsets[d] + pos] = make_int2(ei[e], e);
        atomicAdd(&attr_sum[d], eattr[e]);
        return;
    }
    // ---- ygemm ----
    __shared__ __align__(16) unsigned short s_a[64][136];
    const int yb = blockIdx.x;                        // 0..1563
    const int n0 = (yb >> 1) * 64;
    const int half = yb & 1;
    const int lane = tid & 63, w = tid >> 6;
    const int m16 = lane & 15, quad = lane >> 4;

    // stage A: 64 rows x 256B = 1024 16B-chunks, 4/thread
    #pragma unroll
    for (int i = 0; i < 4; ++i) {
        int c = tid + i * 256;
        int row = c >> 4, col = (c & 15) * 8;
        *(uint4*)&s_a[row][col] = *(const uint4*)(zb + (size_t)(n0 + row) * C_IN + col);
    }

    bf16x8 bfr[4][4];
    {
        const bf16x8* bp = (const bf16x8*)Bpack;
        #pragma unroll
        for (int ks = 0; ks < 4; ++ks)
            #pragma unroll
            for (int nt = 0; nt < 4; ++nt)
                bfr[ks][nt] = bp[((half * 4 + ks) * 16 + (w * 4 + nt)) * 64 + lane];
    }
    __syncthreads();

    f32x4 acc[4][4];
    #pragma unroll
    for (int mt = 0; mt < 4; ++mt)
        #pragma unroll
        for (int nt = 0; nt < 4; ++nt)
            acc[mt][nt] = (f32x4){0.f, 0.f, 0.f, 0.f};

    #pragma unroll
    for (int ks = 0; ks < 4; ++ks) {
        #pragma unroll
        for (int mt = 0; mt < 4; ++mt) {
            bf16x8 a = *(const bf16x8*)&s_a[mt * 16 + m16][ks * 32 + quad * 8];
            #pragma unroll
            for (int nt = 0; nt < 4; ++nt)
                acc[mt][nt] = __builtin_amdgcn_mfma_f32_16x16x32_bf16(
                    a, bfr[ks][nt], acc[mt][nt], 0, 0, 0);
        }
    }

    #pragma unroll
    for (int nt = 0; nt < 4; ++nt) {
        const int c = w * 64 + nt * 16 + m16;           // col within half
        const float b = half ? be1[c] : 0.f;
        #pragma unroll
        for (int mt = 0; mt < 4; ++mt)
            #pragma unroll
            for (int r = 0; r < 4; ++r) {
                const int node = n0 + mt * 16 + quad * 4 + r;
                Y[(size_t)node * YSTRIDE + half * 256 + c] = f2bf(acc[mt][nt][r] + b);
            }
    }
}

// ---------- fused edge elementwise + gather-mean (ONE WAVE per dst node) ----------
// R2-proven structure: 64-thr blocks, 4 edges/iter, record-only cross-iteration
// prefetch (gathers issue same-iter; 22 resident waves/CU hide their latency).
// Records are int2 {src, edge_id}; attr sum comes precomputed from fill.
// Y_hi[dst] + We2 hoisted to registers once per node. Edge dot: 16 lanes per
// edge x 16 channels per lane; 4-stage xor reduce.
// segb is written in-place into the node's own Y_hi bytes (ch 256..415):
// this wave already consumed Y_hi[n]; src gathers touch Y_lo only.
__device__ __forceinline__ float dot8(uint4 q, const float* __restrict__ d,
                                      const float* __restrict__ wv, float p) {
    const unsigned u[4] = {q.x, q.y, q.z, q.w};
    #pragma unroll
    for (int j = 0; j < 4; ++j) {
        const float lo = __uint_as_float(u[j] << 16)         + d[2 * j];
        const float hi = __uint_as_float(u[j] & 0xffff0000u) + d[2 * j + 1];
        p = fmaf(fmaxf(lo, 0.f), wv[2 * j],     p);
        p = fmaf(fmaxf(hi, 0.f), wv[2 * j + 1], p);
    }
    return p;
}

__global__ __launch_bounds__(64, 6) void fused_eg_kernel(
    unsigned short* __restrict__ Y, const unsigned short* __restrict__ zb,
    const int* __restrict__ offsets, const int2* __restrict__ erec,
    const float* __restrict__ attr_sum,
    const float* __restrict__ We2, const float* __restrict__ be2,
    float* __restrict__ edge_out)
{
    const int lane = threadIdx.x;
    const int n = blockIdx.x;
    const int c = lane & 15, g = lane >> 4;           // 16 lanes per edge-slot
    const int beg = offsets[n], end = offsets[n + 1], deg = end - beg;
    const float be2v = be2[0];
    const float asum = attr_sum[n];

    // hoist dst half-row (ch c*8+0..7 and 128+c*8+0..7) + matching We2
    float d0[8], d1[8], w0[8], w1[8];
    {
        const unsigned short* yh = Y + (size_t)n * YSTRIDE + 256;
        uint4 q0 = *(const uint4*)(yh + c * 8);
        uint4 q1 = *(const uint4*)(yh + 128 + c * 8);
        const unsigned a0[4] = {q0.x, q0.y, q0.z, q0.w};
        const unsigned a1[4] = {q1.x, q1.y, q1.z, q1.w};
        #pragma unroll
        for (int j = 0; j < 4; ++j) {
            d0[2 * j]     = __uint_as_float(a0[j] << 16);
            d0[2 * j + 1] = __uint_as_float(a0[j] & 0xffff0000u);
            d1[2 * j]     = __uint_as_float(a1[j] << 16);
            d1[2 * j + 1] = __uint_as_float(a1[j] & 0xffff0000u);
        }
        #pragma unroll
        for (int j = 0; j < 8; ++j) {
            w0[j] = We2[c * 8 + j];
            w1[j] = We2[128 + c * 8 + j];
        }
    }

    float ax = 0.f, ay = 0.f;                  // lane owns z-channels lane*2, lane*2+1
    const int nfull = deg >> 2;
    int i = beg;
    int2 ra, rb, rc, rd;                       // pipelined record prefetch
    if (nfull) { ra = erec[i]; rb = erec[i + 1]; rc = erec[i + 2]; rd = erec[i + 3]; }
    for (int it = 0; it < nfull; ++it) {
        const int2 c0 = ra, c1 = rb, c2 = rc, c3 = rd;
        i += 4;
        if (it + 1 < nfull) {
            ra = erec[i]; rb = erec[i + 1]; rc = erec[i + 2]; rd = erec[i + 3];
        }
        // z-mean: all 64 lanes, all 4 edges
        const unsigned u0 = *(const unsigned*)(zb + (size_t)c0.x * C_IN + lane * 2);
        const unsigned u1 = *(const unsigned*)(zb + (size_t)c1.x * C_IN + lane * 2);
        const unsigned u2 = *(const unsigned*)(zb + (size_t)c2.x * C_IN + lane * 2);
        const unsigned u3 = *(const unsigned*)(zb + (size_t)c3.x * C_IN + lane * 2);
        ax += __uint_as_float(u0 << 16) + __uint_as_float(u1 << 16)
            + __uint_as_float(u2 << 16) + __uint_as_float(u3 << 16);
        ay += __uint_as_float(u0 & 0xffff0000u) + __uint_as_float(u1 & 0xffff0000u)
            + __uint_as_float(u2 & 0xffff0000u) + __uint_as_float(u3 & 0xffff0000u);
        // edge dot: group g owns edge it*4+g
        const int sg = (g == 0) ? c0.x : (g == 1) ? c1.x : (g == 2) ? c2.x : c3.x;
        const int eg = (g == 0) ? c0.y : (g == 1) ? c1.y : (g == 2) ? c2.y : c3.y;
        const unsigned short* yr = Y + (size_t)sg * YSTRIDE;
        const uint4 q0 = *(const uint4*)(yr + c * 8);
        const uint4 q1 = *(const uint4*)(yr + 128 + c * 8);
        float p = dot8(q0, d0, w0, 0.f);
        p = dot8(q1, d1, w1, p);
        p += __shfl_xor(p, 1, 64);
        p += __shfl_xor(p, 2, 64);
        p += __shfl_xor(p, 4, 64);
        p += __shfl_xor(p, 8, 64);
        if (c == 0) edge_out[eg] = p + be2v;
    }
    for (; i < end; ++i) {                     // tail (<=3 edges)
        const int2 r = erec[i];
        const unsigned u = *(const unsigned*)(zb + (size_t)r.x * C_IN + lane * 2);
        ax += __uint_as_float(u << 16);
        ay += __uint_as_float(u & 0xffff0000u);
        const unsigned short* yr = Y + (size_t)r.x * YSTRIDE;
        const uint4 q0 = *(const uint4*)(yr + c * 8);
        const uint4 q1 = *(const uint4*)(yr + 128 + c * 8);
        float p = dot8(q0, d0, w0, 0.f);
        p = dot8(q1, d1, w1, p);
        p += __shfl_xor(p, 1, 64);
        p += __shfl_xor(p, 2, 64);
        p += __shfl_xor(p, 4, 64);
        p += __shfl_xor(p, 8, 64);
        if (lane == 0) edge_out[r.y] = p + be2v;
    }

    const float inv = (deg > 0) ? 1.0f / (float)deg : 0.0f;
    unsigned short* segn = Y + (size_t)n * YSTRIDE + 256;   // in-place: Y_hi is dead now
    ushort2 o; o.x = f2bf(ax * inv); o.y = f2bf(ay * inv);
    *(ushort2*)(segn + lane * 2) = o;
    if (lane < 16) {
        ushort2 pz; pz.x = (lane == 0) ? f2bf(asum * inv) : (unsigned short)0; pz.y = 0;
        *(ushort2*)(segn + 128 + lane * 2) = pz;   // attr @128, zeros 129..159
    }
}

// ---------- node MLP: bf16 MFMA, both layers, h via LDS round-trip ----------
// segb lives in Y ch 256..415 of each row (stride YSTRIDE).
__global__ __launch_bounds__(256, 2) void node_mfma_kernel(
    const unsigned short* __restrict__ segb, const unsigned short* __restrict__ Wa1b,
    const float* __restrict__ ba1, const unsigned short* __restrict__ Wa2b,
    const float* __restrict__ ba2, float* __restrict__ x_out)
{
    __shared__ __align__(16) unsigned short s_a[64][168];
    __shared__ __align__(16) unsigned short s_h[64][264];
    const int tid  = threadIdx.x;
    const int lane = tid & 63, w = tid >> 6;
    const int m16 = lane & 15, quad = lane >> 4;
    const int n0 = blockIdx.x * 64;

    {
        const unsigned short* src = segb + (size_t)n0 * YSTRIDE + 256;
        #pragma unroll
        for (int i = 0; i < 5; ++i) {
            int c = tid + i * 256;
            int row = c / 20, col = c - row * 20;
            *(uint4*)&s_a[row][col * 8] =
                *(const uint4*)(src + (size_t)row * YSTRIDE + col * 8);
        }
    }

    bf16x8 bfr1[5][4];
    {
        const bf16x8* bp = (const bf16x8*)Wa1b;
        #pragma unroll
        for (int ks = 0; ks < 5; ++ks)
            #pragma unroll
            for (int nt = 0; nt < 4; ++nt)
                bfr1[ks][nt] = bp[(ks * 16 + (w * 4 + nt)) * 64 + lane];
    }
    __syncthreads();

    f32x4 acc1[4][4];
    #pragma unroll
    for (int mt = 0; mt < 4; ++mt)
        #pragma unroll
        for (int nt = 0; nt < 4; ++nt)
            acc1[mt][nt] = (f32x4){0.f, 0.f, 0.f, 0.f};

    #pragma unroll
    for (int ks = 0; ks < 5; ++ks) {
        #pragma unroll
        for (int mt = 0; mt < 4; ++mt) {
            bf16x8 a = *(const bf16x8*)&s_a[mt * 16 + m16][ks * 32 + quad * 8];
            #pragma unroll
            for (int nt = 0; nt < 4; ++nt)
                acc1[mt][nt] = __builtin_amdgcn_mfma_f32_16x16x32_bf16(
                    a, bfr1[ks][nt], acc1[mt][nt], 0, 0, 0);
        }
    }

    #pragma unroll
    for (int nt = 0; nt < 4; ++nt) {
        const int chan = w * 64 + nt * 16 + m16;
        const float b1 = ba1[chan];
        #pragma unroll
        for (int mt = 0; mt < 4; ++mt)
            #pragma unroll
            for (int r = 0; r < 4; ++r) {
                const int node = mt * 16 + quad * 4 + r;
                s_h[node][chan] = f2bf(fmaxf(acc1[mt][nt][r] + b1, 0.f));
            }
    }

    bf16x8 bfr2[8][2];
    {
        const bf16x8* bp = (const bf16x8*)Wa2b;
        #pragma unroll
        for (int ks = 0; ks < 8; ++ks)
            #pragma unroll
            for (int nt = 0; nt < 2; ++nt)
                bfr2[ks][nt] = bp[(ks * 8 + (w * 2 + nt)) * 64 + lane];
    }
    __syncthreads();

    f32x4 acc2[4][2];
    #pragma unroll
    for (int mt = 0; mt < 4; ++mt)
        #pragma unroll
        for (int nt = 0; nt < 2; ++nt)
            acc2[mt][nt] = (f32x4){0.f, 0.f, 0.f, 0.f};

    #pragma unroll
    for (int ks = 0; ks < 8; ++ks) {
        #pragma unroll
        for (int mt = 0; mt < 4; ++mt) {
            bf16x8 a = *(const bf16x8*)&s_h[mt * 16 + m16][ks * 32 + quad * 8];
            #pragma unroll
            for (int nt = 0; nt < 2; ++nt)
                acc2[mt][nt] = __builtin_amdgcn_mfma_f32_16x16x32_bf16(
                    a, bfr2[ks][nt], acc2[mt][nt], 0, 0, 0);
        }
    }

    #pragma unroll
    for (int nt = 0; nt < 2; ++nt) {
        const int j = w * 32 + nt * 16 + m16;
        const float b2 = ba2[j];
        #pragma unroll
        for (int mt = 0; mt < 4; ++mt)
            #pragma unroll
            for (int r = 0; r < 4; ++r) {
                const int node = n0 + mt * 16 + quad * 4 + r;
                if (node < N_NODES)
                    x_out[(size_t)node * C_OUT + j] = acc2[mt][nt][r] + b2;
            }
    }
}

// ---------- launch ----------
// ws layout (bytes), total ~71.6 MB:
//   Y         51,249,152   (50048 x 512 bf16; ch 256..415 become segb in-place)
//   zb        12,812,288   (50048 rows; 50000 valid, tail garbage never used)
//   Bpack        131,072
//   Wa1b          81,920
//   Wa2b          65,536
//   cnt          200,704   (50176 ints, zero-padded; consumed by fill's atomicSub)
//   attr_sum     200,704   (adjacent to cnt: one memset zeroes both)
//   offsets      200,704   (padded to 50176 ints for scan)
//   erec       6,400,000   (800000 x int2 {src, edge_id})

extern "C" void kernel_launch(void* const* d_in, const int* in_sizes, int n_in,
                              void* d_out, int out_size, void* d_ws, size_t ws_size,
                              hipStream_t stream) {
    const float* z     = (const float*)d_in[0];
    const int*   ei    = (const int*)d_in[1];     // int32 per harness contract
    const float* eattr = (const float*)d_in[2];
    const float* Wa1   = (const float*)d_in[3];
    const float* ba1   = (const float*)d_in[4];
    const float* Wa2   = (const float*)d_in[5];
    const float* ba2   = (const float*)d_in[6];
    const float* We1   = (const float*)d_in[7];
    const float* be1   = (const float*)d_in[8];
    const float* We2   = (const float*)d_in[9];
    const float* be2   = (const float*)d_in[10];

    float* x_out    = (float*)d_out;
    float* edge_out = x_out + (size_t)N_NODES * C_OUT;

    char* wsb = (char*)d_ws;
    size_t off = 0;
    unsigned short* Y        = (unsigned short*)(wsb + off); off += 51249152;
    unsigned short* zb       = (unsigned short*)(wsb + off); off += 12812288;
    unsigned short* Bpack    = (unsigned short*)(wsb + off); off += 131072;
    unsigned short* Wa1b     = (unsigned short*)(wsb + off); off += 81920;
    unsigned short* Wa2b     = (unsigned short*)(wsb + off); off += 65536;
    int*            cnt      = (int*)(wsb + off);            off += 200704;
    float*          attr_sum = (float*)(wsb + off);          off += 200704;
    int*            offsets  = (int*)(wsb + off);            off += 200704;
    int2*           erec     = (int2*)(wsb + off);           off += 6400000;

    hipMemsetAsync(cnt, 0, 2 * 200704, stream);   // cnt + attr_sum (adjacent)

    prep_kernel<<<6250 + 3125 + 32 + 20 + 16, 256, 0, stream>>>(
        z, ei, We1, Wa1, Wa2, zb, cnt, Bpack, Wa1b, Wa2b);

    scan_kernel<<<1, 1024, 0, stream>>>(cnt, offsets);

    fy_kernel<<<1564 + 3125, 256, 0, stream>>>(ei, eattr, offsets, cnt, erec,
                                               attr_sum, zb, Bpack, be1, Y);

    fused_eg_kernel<<<N_NODES, 64, 0, stream>>>(
        Y, zb, offsets, erec, attr_sum, We2, be2, edge_out);

    node_mfma_kernel<<<(N_NODES + 63) / 64, 256, 0, stream>>>(Y, Wa1b, ba1, Wa2b,
                                                              ba2, x_out);
}

// Round 5
// 297.907 us; speedup vs baseline: 1.4165x; 1.1805x over previous
//
#include <hip/hip_runtime.h>

#define N_NODES 50000
#define N_EDGES 800000
#define C_IN    128
#define C_HID   256
#define C_OUT   128
#define YSTRIDE 512       // bf16: [y_src 0..255 | y_dst 256..511]; after fused kernel,
                          // ch 256..415 of each row are overwritten with segb
                          // [z-mean 0..127 | attr 128 | zeros 129..159]

typedef __bf16 bf16x8 __attribute__((ext_vector_type(8)));
typedef float  f32x4  __attribute__((ext_vector_type(4)));

__device__ __forceinline__ unsigned short f2bf(float x) {
    unsigned u = __float_as_uint(x);
    u = (u + 0x7FFF + ((u >> 16) & 1)) >> 16;   // RNE
    return (unsigned short)u;
}

// ---------- fused prep: cast_z | hist(+epos capture) | bpack | wa1b | wa2b ----------
// The hist atomicAdd's return value IS the within-node slot index — capturing it
// into epos[] makes the later fill pass atomic-free (was: a second atomicSub
// chain + attr atomicAdd = 1.6M extra atomics and ~100 MB of line-bounce).
__global__ __launch_bounds__(256) void prep_kernel(
    const float* __restrict__ z, const int* __restrict__ ei,
    const float* __restrict__ We1, const float* __restrict__ Wa1,
    const float* __restrict__ Wa2,
    unsigned short* __restrict__ zb, int* __restrict__ cnt, int* __restrict__ epos,
    unsigned short* __restrict__ Bpack, unsigned short* __restrict__ Wa1b,
    unsigned short* __restrict__ Wa2b)
{
    const int b = blockIdx.x;
    const int tid = threadIdx.x;
    if (b < 6250) {                                   // cast_z: 6250*256 = 1.6M float4
        int t = b * 256 + tid;
        float4 v = ((const float4*)z)[t];
        ushort4 o;
        o.x = f2bf(v.x); o.y = f2bf(v.y); o.z = f2bf(v.z); o.w = f2bf(v.w);
        ((ushort4*)zb)[t] = o;
    } else if (b < 6250 + 3125) {                     // hist: 3125*256 = 800000
        int e = (b - 6250) * 256 + tid;
        epos[e] = atomicAdd(&cnt[ei[N_EDGES + e]], 1);
    } else if (b < 6250 + 3125 + 32) {                // Bpack (We1 B-frags, 8ks x 16nt)
        int t = (b - 6250 - 3125) * 256 + tid;        // 8192 lane-slots
        int lane = t & 63, nt = (t >> 6) & 15, ks = t >> 10;
        int n  = nt * 16 + (lane & 15);
        int kb = ks * 32 + (lane >> 4) * 8;
        #pragma unroll
        for (int j = 0; j < 8; ++j)
            Bpack[t * 8 + j] = f2bf(We1[(kb + j) * C_HID + n]);
    } else if (b < 6250 + 3125 + 32 + 20) {           // Wa1b (node layer1)
        int t = (b - 6250 - 3125 - 32) * 256 + tid;
        if (t >= 5 * 16 * 64) return;
        int lane = t & 63, nt = (t >> 6) & 15, ks = t >> 10;
        int n = nt * 16 + (lane & 15);
        #pragma unroll
        for (int j = 0; j < 8; ++j) {
            int k = ks * 32 + (lane >> 4) * 8 + j;
            float v = 0.f;
            if (k < 128)       v = Wa1[(k + 1) * C_HID + n];
            else if (k == 128) v = Wa1[0 * C_HID + n];
            Wa1b[t * 8 + j] = f2bf(v);
        }
    } else {                                          // Wa2b (node layer2)
        int t = (b - 6250 - 3125 - 32 - 20) * 256 + tid;
        if (t >= 8 * 8 * 64) return;
        int lane = t & 63, nt = (t >> 6) & 7, ks = t >> 9;
        int n  = nt * 16 + (lane & 15);
        int kb = ks * 32 + (lane >> 4) * 8;
        #pragma unroll
        for (int j = 0; j < 8; ++j)
            Wa2b[t * 8 + j] = f2bf(Wa2[(kb + j) * C_OUT + n]);
    }
}

// ---------- CSR scan: 1024 threads, 49 ints/thread (1024*49 = 50176 exact) ----------
// cnt zero-padded to 50176; offsets padded to 50176. offsets[50000] lands
// correctly (cnt[50000..] == 0 so the running prefix is total edges there).
__global__ __launch_bounds__(1024) void scan_kernel(const int* __restrict__ cnt,
                                                    int* __restrict__ offsets) {
    const int tid = threadIdx.x;
    const int base = tid * 49;
    int c[49];
    int sum = 0;
    #pragma unroll
    for (int i = 0; i < 49; ++i) { c[i] = cnt[base + i]; sum += c[i]; }
    const int lane = tid & 63, w = tid >> 6;          // 16 waves
    int v = sum;
    #pragma unroll
    for (int off = 1; off < 64; off <<= 1) {
        int t = __shfl_up(v, off, 64);
        if (lane >= off) v += t;
    }
    __shared__ int s_w[16];
    if (lane == 63) s_w[w] = v;
    __syncthreads();
    int wbase = 0;
    #pragma unroll
    for (int i = 0; i < 16; ++i) wbase += (i < w) ? s_w[i] : 0;
    int run = wbase + v - sum;
    #pragma unroll
    for (int i = 0; i < 49; ++i) { offsets[base + i] = run; run += c[i]; }
}

// ---------- merged Y GEMM + fill (ygemm blocks FIRST: long MFMA blocks flood ----------
// the CUs; short streaming fill blocks drain into freed slots).
// Blocks 0..1563: ygemm — Y[:,0:256] = zb@We1_top ; Y[:,256:512] = zb@We1_bot+be1.
//   M=50048 x K=128 x N=256 per half; wave owns 64 cols of its half.
// Blocks 1564..4688: fill — ATOMIC-FREE: slot = offsets[d] + epos[e] (epos was
//   captured from the hist atomic in prep). One 16-B record store per edge.
__global__ __launch_bounds__(256, 2) void fy_kernel(
    const int* __restrict__ ei, const float* __restrict__ eattr,
    const int* __restrict__ offsets, const int* __restrict__ epos,
    int4* __restrict__ erec,
    const unsigned short* __restrict__ zb, const unsigned short* __restrict__ Bpack,
    const float* __restrict__ be1, unsigned short* __restrict__ Y)
{
    const int tid = threadIdx.x;
    if (blockIdx.x >= 1564) {                         // ---- fill ----
        int e = (blockIdx.x - 1564) * 256 + tid;      // 3125*256 = 800000 exact
        int d = ei[N_EDGES + e];
        erec[offsets[d] + epos[e]] = make_int4(ei[e], e, __float_as_int(eattr[e]), 0);
        return;
    }
    // ---- ygemm ----
    __shared__ __align__(16) unsigned short s_a[64][136];
    const int yb = blockIdx.x;                        // 0..1563
    const int n0 = (yb >> 1) * 64;
    const int half = yb & 1;
    const int lane = tid & 63, w = tid >> 6;
    const int m16 = lane & 15, quad = lane >> 4;

    // stage A: 64 rows x 256B = 1024 16B-chunks, 4/thread
    #pragma unroll
    for (int i = 0; i < 4; ++i) {
        int c = tid + i * 256;
        int row = c >> 4, col = (c & 15) * 8;
        *(uint4*)&s_a[row][col] = *(const uint4*)(zb + (size_t)(n0 + row) * C_IN + col);
    }

    bf16x8 bfr[4][4];
    {
        const bf16x8* bp = (const bf16x8*)Bpack;
        #pragma unroll
        for (int ks = 0; ks < 4; ++ks)
            #pragma unroll
            for (int nt = 0; nt < 4; ++nt)
                bfr[ks][nt] = bp[((half * 4 + ks) * 16 + (w * 4 + nt)) * 64 + lane];
    }
    __syncthreads();

    f32x4 acc[4][4];
    #pragma unroll
    for (int mt = 0; mt < 4; ++mt)
        #pragma unroll
        for (int nt = 0; nt < 4; ++nt)
            acc[mt][nt] = (f32x4){0.f, 0.f, 0.f, 0.f};

    #pragma unroll
    for (int ks = 0; ks < 4; ++ks) {
        #pragma unroll
        for (int mt = 0; mt < 4; ++mt) {
            bf16x8 a = *(const bf16x8*)&s_a[mt * 16 + m16][ks * 32 + quad * 8];
            #pragma unroll
            for (int nt = 0; nt < 4; ++nt)
                acc[mt][nt] = __builtin_amdgcn_mfma_f32_16x16x32_bf16(
                    a, bfr[ks][nt], acc[mt][nt], 0, 0, 0);
        }
    }

    #pragma unroll
    for (int nt = 0; nt < 4; ++nt) {
        const int c = w * 64 + nt * 16 + m16;           // col within half
        const float b = half ? be1[c] : 0.f;
        #pragma unroll
        for (int mt = 0; mt < 4; ++mt)
            #pragma unroll
            for (int r = 0; r < 4; ++r) {
                const int node = n0 + mt * 16 + quad * 4 + r;
                Y[(size_t)node * YSTRIDE + half * 256 + c] = f2bf(acc[mt][nt][r] + b);
            }
    }
}

// ---------- fused edge elementwise + gather-mean (ONE WAVE per dst node) ----------
// R2-proven structure: 64-thr blocks, 4 edges/iter, record-only cross-iteration
// prefetch (gathers issue same-iter; ~22 resident waves/CU hide their latency).
// Records are int4 {src, edge_id, attr_bits, 0}; attr sum is a free uniform
// accumulate. Y_hi[dst] + We2 hoisted to registers once per node. Edge dot:
// 16 lanes per edge x 16 channels per lane; 4-stage xor reduce.
// segb is written in-place into the node's own Y_hi bytes (ch 256..415):
// this wave already consumed Y_hi[n]; src gathers touch Y_lo only.
__device__ __forceinline__ float dot8(uint4 q, const float* __restrict__ d,
                                      const float* __restrict__ wv, float p) {
    const unsigned u[4] = {q.x, q.y, q.z, q.w};
    #pragma unroll
    for (int j = 0; j < 4; ++j) {
        const float lo = __uint_as_float(u[j] << 16)         + d[2 * j];
        const float hi = __uint_as_float(u[j] & 0xffff0000u) + d[2 * j + 1];
        p = fmaf(fmaxf(lo, 0.f), wv[2 * j],     p);
        p = fmaf(fmaxf(hi, 0.f), wv[2 * j + 1], p);
    }
    return p;
}

__global__ __launch_bounds__(64, 6) void fused_eg_kernel(
    unsigned short* __restrict__ Y, const unsigned short* __restrict__ zb,
    const int* __restrict__ offsets, const int4* __restrict__ erec,
    const float* __restrict__ We2, const float* __restrict__ be2,
    float* __restrict__ edge_out)
{
    const int lane = threadIdx.x;
    const int n = blockIdx.x;
    const int c = lane & 15, g = lane >> 4;           // 16 lanes per edge-slot
    const int beg = offsets[n], end = offsets[n + 1], deg = end - beg;
    const float be2v = be2[0];

    // hoist dst half-row (ch c*8+0..7 and 128+c*8+0..7) + matching We2
    float d0[8], d1[8], w0[8], w1[8];
    {
        const unsigned short* yh = Y + (size_t)n * YSTRIDE + 256;
        uint4 q0 = *(const uint4*)(yh + c * 8);
        uint4 q1 = *(const uint4*)(yh + 128 + c * 8);
        const unsigned a0[4] = {q0.x, q0.y, q0.z, q0.w};
        const unsigned a1[4] = {q1.x, q1.y, q1.z, q1.w};
        #pragma unroll
        for (int j = 0; j < 4; ++j) {
            d0[2 * j]     = __uint_as_float(a0[j] << 16);
            d0[2 * j + 1] = __uint_as_float(a0[j] & 0xffff0000u);
            d1[2 * j]     = __uint_as_float(a1[j] << 16);
            d1[2 * j + 1] = __uint_as_float(a1[j] & 0xffff0000u);
        }
        #pragma unroll
        for (int j = 0; j < 8; ++j) {
            w0[j] = We2[c * 8 + j];
            w1[j] = We2[128 + c * 8 + j];
        }
    }

    float ax = 0.f, ay = 0.f;                  // lane owns z-channels lane*2, lane*2+1
    float asum = 0.f;                          // uniform across wave
    const int nfull = deg >> 2;
    int i = beg;
    int4 ra, rb, rc, rd;                       // pipelined record prefetch
    if (nfull) { ra = erec[i]; rb = erec[i + 1]; rc = erec[i + 2]; rd = erec[i + 3]; }
    for (int it = 0; it < nfull; ++it) {
        const int4 c0 = ra, c1 = rb, c2 = rc, c3 = rd;
        i += 4;
        if (it + 1 < nfull) {
            ra = erec[i]; rb = erec[i + 1]; rc = erec[i + 2]; rd = erec[i + 3];
        }
        asum += __int_as_float(c0.z) + __int_as_float(c1.z)
              + __int_as_float(c2.z) + __int_as_float(c3.z);
        // z-mean: all 64 lanes, all 4 edges
        const unsigned u0 = *(const unsigned*)(zb + (size_t)c0.x * C_IN + lane * 2);
        const unsigned u1 = *(const unsigned*)(zb + (size_t)c1.x * C_IN + lane * 2);
        const unsigned u2 = *(const unsigned*)(zb + (size_t)c2.x * C_IN + lane * 2);
        const unsigned u3 = *(const unsigned*)(zb + (size_t)c3.x * C_IN + lane * 2);
        ax += __uint_as_float(u0 << 16) + __uint_as_float(u1 << 16)
            + __uint_as_float(u2 << 16) + __uint_as_float(u3 << 16);
        ay += __uint_as_float(u0 & 0xffff0000u) + __uint_as_float(u1 & 0xffff0000u)
            + __uint_as_float(u2 & 0xffff0000u) + __uint_as_float(u3 & 0xffff0000u);
        // edge dot: group g owns edge it*4+g
        const int sg = (g == 0) ? c0.x : (g == 1) ? c1.x : (g == 2) ? c2.x : c3.x;
        const int eg = (g == 0) ? c0.y : (g == 1) ? c1.y : (g == 2) ? c2.y : c3.y;
        const unsigned short* yr = Y + (size_t)sg * YSTRIDE;
        const uint4 q0 = *(const uint4*)(yr + c * 8);
        const uint4 q1 = *(const uint4*)(yr + 128 + c * 8);
        float p = dot8(q0, d0, w0, 0.f);
        p = dot8(q1, d1, w1, p);
        p += __shfl_xor(p, 1, 64);
        p += __shfl_xor(p, 2, 64);
        p += __shfl_xor(p, 4, 64);
        p += __shfl_xor(p, 8, 64);
        if (c == 0) edge_out[eg] = p + be2v;
    }
    for (; i < end; ++i) {                     // tail (<=3 edges)
        const int4 r = erec[i];
        asum += __int_as_float(r.z);
        const unsigned u = *(const unsigned*)(zb + (size_t)r.x * C_IN + lane * 2);
        ax += __uint_as_float(u << 16);
        ay += __uint_as_float(u & 0xffff0000u);
        const unsigned short* yr = Y + (size_t)r.x * YSTRIDE;
        const uint4 q0 = *(const uint4*)(yr + c * 8);
        const uint4 q1 = *(const uint4*)(yr + 128 + c * 8);
        float p = dot8(q0, d0, w0, 0.f);
        p = dot8(q1, d1, w1, p);
        p += __shfl_xor(p, 1, 64);
        p += __shfl_xor(p, 2, 64);
        p += __shfl_xor(p, 4, 64);
        p += __shfl_xor(p, 8, 64);
        if (lane == 0) edge_out[r.y] = p + be2v;
    }

    const float inv = (deg > 0) ? 1.0f / (float)deg : 0.0f;
    unsigned short* segn = Y + (size_t)n * YSTRIDE + 256;   // in-place: Y_hi is dead now
    ushort2 o; o.x = f2bf(ax * inv); o.y = f2bf(ay * inv);
    *(ushort2*)(segn + lane * 2) = o;
    if (lane < 16) {
        ushort2 pz; pz.x = (lane == 0) ? f2bf(asum * inv) : (unsigned short)0; pz.y = 0;
        *(ushort2*)(segn + 128 + lane * 2) = pz;   // attr @128, zeros 129..159
    }
}

// ---------- node MLP: bf16 MFMA, both layers, h via LDS round-trip ----------
// segb lives in Y ch 256..415 of each row (stride YSTRIDE).
__global__ __launch_bounds__(256, 2) void node_mfma_kernel(
    const unsigned short* __restrict__ segb, const unsigned short* __restrict__ Wa1b,
    const float* __restrict__ ba1, const unsigned short* __restrict__ Wa2b,
    const float* __restrict__ ba2, float* __restrict__ x_out)
{
    __shared__ __align__(16) unsigned short s_a[64][168];
    __shared__ __align__(16) unsigned short s_h[64][264];
    const int tid  = threadIdx.x;
    const int lane = tid & 63, w = tid >> 6;
    const int m16 = lane & 15, quad = lane >> 4;
    const int n0 = blockIdx.x * 64;

    {
        const unsigned short* src = segb + (size_t)n0 * YSTRIDE + 256;
        #pragma unroll
        for (int i = 0; i < 5; ++i) {
            int c = tid + i * 256;
            int row = c / 20, col = c - row * 20;
            *(uint4*)&s_a[row][col * 8] =
                *(const uint4*)(src + (size_t)row * YSTRIDE + col * 8);
        }
    }

    bf16x8 bfr1[5][4];
    {
        const bf16x8* bp = (const bf16x8*)Wa1b;
        #pragma unroll
        for (int ks = 0; ks < 5; ++ks)
            #pragma unroll
            for (int nt = 0; nt < 4; ++nt)
                bfr1[ks][nt] = bp[(ks * 16 + (w * 4 + nt)) * 64 + lane];
    }
    __syncthreads();

    f32x4 acc1[4][4];
    #pragma unroll
    for (int mt = 0; mt < 4; ++mt)
        #pragma unroll
        for (int nt = 0; nt < 4; ++nt)
            acc1[mt][nt] = (f32x4){0.f, 0.f, 0.f, 0.f};

    #pragma unroll
    for (int ks = 0; ks < 5; ++ks) {
        #pragma unroll
        for (int mt = 0; mt < 4; ++mt) {
            bf16x8 a = *(const bf16x8*)&s_a[mt * 16 + m16][ks * 32 + quad * 8];
            #pragma unroll
            for (int nt = 0; nt < 4; ++nt)
                acc1[mt][nt] = __builtin_amdgcn_mfma_f32_16x16x32_bf16(
                    a, bfr1[ks][nt], acc1[mt][nt], 0, 0, 0);
        }
    }

    #pragma unroll
    for (int nt = 0; nt < 4; ++nt) {
        const int chan = w * 64 + nt * 16 + m16;
        const float b1 = ba1[chan];
        #pragma unroll
        for (int mt = 0; mt < 4; ++mt)
            #pragma unroll
            for (int r = 0; r < 4; ++r) {
                const int node = mt * 16 + quad * 4 + r;
                s_h[node][chan] = f2bf(fmaxf(acc1[mt][nt][r] + b1, 0.f));
            }
    }

    bf16x8 bfr2[8][2];
    {
        const bf16x8* bp = (const bf16x8*)Wa2b;
        #pragma unroll
        for (int ks = 0; ks < 8; ++ks)
            #pragma unroll
            for (int nt = 0; nt < 2; ++nt)
                bfr2[ks][nt] = bp[(ks * 8 + (w * 2 + nt)) * 64 + lane];
    }
    __syncthreads();

    f32x4 acc2[4][2];
    #pragma unroll
    for (int mt = 0; mt < 4; ++mt)
        #pragma unroll
        for (int nt = 0; nt < 2; ++nt)
            acc2[mt][nt] = (f32x4){0.f, 0.f, 0.f, 0.f};

    #pragma unroll
    for (int ks = 0; ks < 8; ++ks) {
        #pragma unroll
        for (int mt = 0; mt < 4; ++mt) {
            bf16x8 a = *(const bf16x8*)&s_h[mt * 16 + m16][ks * 32 + quad * 8];
            #pragma unroll
            for (int nt = 0; nt < 2; ++nt)
                acc2[mt][nt] = __builtin_amdgcn_mfma_f32_16x16x32_bf16(
                    a, bfr2[ks][nt], acc2[mt][nt], 0, 0, 0);
        }
    }

    #pragma unroll
    for (int nt = 0; nt < 2; ++nt) {
        const int j = w * 32 + nt * 16 + m16;
        const float b2 = ba2[j];
        #pragma unroll
        for (int mt = 0; mt < 4; ++mt)
            #pragma unroll
            for (int r = 0; r < 4; ++r) {
                const int node = n0 + mt * 16 + quad * 4 + r;
                if (node < N_NODES)
                    x_out[(size_t)node * C_OUT + j] = acc2[mt][nt][r] + b2;
            }
    }
}

// ---------- launch ----------
// ws layout (bytes), total ~81.1 MB:
//   Y         51,249,152   (50048 x 512 bf16; ch 256..415 become segb in-place)
//   zb        12,812,288   (50048 rows; 50000 valid, tail garbage never used)
//   Bpack        131,072
//   Wa1b          81,920
//   Wa2b          65,536
//   cnt          200,704   (50176 ints, zero-padded for scan; NOT consumed by fill)
//   offsets      200,704   (padded to 50176 ints for scan)
//   epos       3,200,000   (per-edge within-node slot, captured from hist atomic)
//   erec      12,800,000   (800000 x int4 {src, edge_id, attr_bits, 0})

extern "C" void kernel_launch(void* const* d_in, const int* in_sizes, int n_in,
                              void* d_out, int out_size, void* d_ws, size_t ws_size,
                              hipStream_t stream) {
    const float* z     = (const float*)d_in[0];
    const int*   ei    = (const int*)d_in[1];     // int32 per harness contract
    const float* eattr = (const float*)d_in[2];
    const float* Wa1   = (const float*)d_in[3];
    const float* ba1   = (const float*)d_in[4];
    const float* Wa2   = (const float*)d_in[5];
    const float* ba2   = (const float*)d_in[6];
    const float* We1   = (const float*)d_in[7];
    const float* be1   = (const float*)d_in[8];
    const float* We2   = (const float*)d_in[9];
    const float* be2   = (const float*)d_in[10];

    float* x_out    = (float*)d_out;
    float* edge_out = x_out + (size_t)N_NODES * C_OUT;

    char* wsb = (char*)d_ws;
    size_t off = 0;
    unsigned short* Y        = (unsigned short*)(wsb + off); off += 51249152;
    unsigned short* zb       = (unsigned short*)(wsb + off); off += 12812288;
    unsigned short* Bpack    = (unsigned short*)(wsb + off); off += 131072;
    unsigned short* Wa1b     = (unsigned short*)(wsb + off); off += 81920;
    unsigned short* Wa2b     = (unsigned short*)(wsb + off); off += 65536;
    int*            cnt      = (int*)(wsb + off);            off += 200704;
    int*            offsets  = (int*)(wsb + off);            off += 200704;
    int*            epos     = (int*)(wsb + off);            off += 3200000;
    int4*           erec     = (int4*)(wsb + off);           off += 12800000;

    hipMemsetAsync(cnt, 0, 200704, stream);

    prep_kernel<<<6250 + 3125 + 32 + 20 + 16, 256, 0, stream>>>(
        z, ei, We1, Wa1, Wa2, zb, cnt, epos, Bpack, Wa1b, Wa2b);

    scan_kernel<<<1, 1024, 0, stream>>>(cnt, offsets);

    fy_kernel<<<1564 + 3125, 256, 0, stream>>>(ei, eattr, offsets, epos, erec,
                                               zb, Bpack, be1, Y);

    fused_eg_kernel<<<N_NODES, 64, 0, stream>>>(
        Y, zb, offsets, erec, We2, be2, edge_out);

    node_mfma_kernel<<<(N_NODES + 63) / 64, 256, 0, stream>>>(Y, Wa1b, ba1, Wa2b,
                                                              ba2, x_out);
}